// Round 16
// baseline (862.077 us; speedup 1.0000x reference)
//
#include <hip/hip_runtime.h>
#include <hip/hip_cooperative_groups.h>
#include <stdint.h>

namespace cg = cooperative_groups;

#define GRID_SZ 0.05f
#define BN_EPS 1e-5f
#define FLAG_MAGIC 0x7FECA110

typedef __attribute__((ext_vector_type(8))) short bf16x8;
typedef __attribute__((ext_vector_type(4))) float f32x4;

// ---------------- ws layout (byte offsets) ----------------
#define WS_START   0         // 24 uints: per-batch min bits / max bits
#define WS_DIMS    96        // 3 ints
#define WS_CHSUM   128       // 256 f
#define WS_CHSQ    1152
#define WS_AC      2176
#define WS_BC      3200
#define WS_W1B     4224      // 256*128 bf16 = 65536
#define WS_W2B     69760     // 256*256 bf16 = 131072
#define WS_GRAM    200832    // 128*128 f = 65536
#define WS_CSUM    266368    // 128 f = 512
#define WS_HIST    266880    // 65536 ints = 262144
#define WS_RANK    529024    // 65537 ints (+pad) = 262208
#define WS_CURS    791296    // 65536 ints = 262144 (doubles as boundary flag in gemmB)
#define WS_BSUM    1053440   // 256 int2 = 2048
#define WS_XYZS    1055488   // 65536*3 f = 786432
#define WS_LIN     1841920   // N ints
#define WS_PERM    2641920   // N ints (xbf=true: vox_sorted; xbf=false: perm)
#define WS_XB      3441920   // N*128 bf16 (SORTED order when xbf=true)

__device__ __forceinline__ short f2bf(float f) {
  unsigned u = __float_as_uint(f);
  u += 0x7FFFu + ((u >> 16) & 1u);   // round-to-nearest-even
  return (short)(u >> 16);
}

__device__ __forceinline__ bf16x8 load_frag(const float* p) {
  f32x4 a = *(const f32x4*)p;
  f32x4 b = *(const f32x4*)(p + 4);
  bf16x8 r;
  r[0] = f2bf(a[0]); r[1] = f2bf(a[1]); r[2] = f2bf(a[2]); r[3] = f2bf(a[3]);
  r[4] = f2bf(b[0]); r[5] = f2bf(b[1]); r[6] = f2bf(b[2]); r[7] = f2bf(b[3]);
  return r;
}

__device__ __forceinline__ int batch_of(int p, const int* offs, int nb) {
  int b = 0;
  while (b < nb - 1 && p >= offs[b]) b++;
  return b;
}

// decode monotonic-u16 -> float
__device__ __forceinline__ float dec16(unsigned e) {
  unsigned us = (e & 0x8000u) ? (e & 0x7FFFu) : (~e & 0xFFFFu);
  return __uint_as_float(us << 16);
}

// dims (max coord per axis) from per-batch min/max corners; exact vs reference
__device__ __forceinline__ void dims_of(const unsigned* gstart, int nb,
                                        int& m0, int& m1, int& m2) {
  m0 = 0; m1 = 0; m2 = 0;
  for (int b = 0; b < nb; b++) {
    float s0 = __uint_as_float(gstart[b * 3 + 0]);
    float s1 = __uint_as_float(gstart[b * 3 + 1]);
    float s2 = __uint_as_float(gstart[b * 3 + 2]);
    float x0 = __uint_as_float(gstart[12 + b * 3 + 0]);
    float x1 = __uint_as_float(gstart[12 + b * 3 + 1]);
    float x2 = __uint_as_float(gstart[12 + b * 3 + 2]);
    m0 = max(m0, (int)floorf((x0 - s0) / GRID_SZ));
    m1 = max(m1, (int)floorf((x1 - s1) / GRID_SZ));
    m2 = max(m2, (int)floorf((x2 - s2) / GRID_SZ));
  }
}

// ---------------- init + weight conversion (fused; featN=0 in xbf path) ------------
__global__ void k_init(unsigned* featU, size_t featN, int* hist, float* xyzs,
                       float* chsum, float* chsq, float* gram, float* csum,
                       unsigned* gstart,
                       const float* __restrict__ W1, const float* __restrict__ W2,
                       short* __restrict__ W1b, short* __restrict__ W2b) {
  size_t i = (size_t)blockIdx.x * blockDim.x + threadIdx.x;
  size_t stride = (size_t)gridDim.x * blockDim.x;
  if (i < 4096) *(bf16x8*)(W1b + i * 8) = load_frag(W1 + i * 8);
  else if (i < 12288) { size_t j = i - 4096; *(bf16x8*)(W2b + j * 8) = load_frag(W2 + j * 8); }
  for (size_t j = i; j < featN; j += stride) featU[j] = 0u;
  for (size_t j = i; j < 65536; j += stride) hist[j] = 0;
  for (size_t j = i; j < 65536u * 3; j += stride) xyzs[j] = 0.f;
  for (size_t j = i; j < 16384; j += stride) gram[j] = 0.f;
  if (i < 256) { chsum[i] = 0.f; chsq[i] = 0.f; }
  if (i < 128) csum[i] = 0.f;
  if (i < 12) gstart[i] = 0x7F800000u;    // +inf bits (min half)
  else if (i < 24) gstart[i] = 0u;        // 0 bits (max half; pos >= 0)
}

// ======= cooperative fused voxel pipeline: min/max -> hist -> scan -> scatter ======
__global__ __launch_bounds__(256, 4) void k_voxel(
    const float* __restrict__ pos, const int* __restrict__ offs, int N, int nb,
    unsigned* gstart, int* gdims, int* lin, int* hist, float* xyzs,
    int2* bsum, int* rank, int* cursor,
    const float* __restrict__ X, short* __restrict__ Xb, int* permvox,
    float* out_inv, float* out_xyz, float* out_off, unsigned* featU) {
  cg::grid_group grid = cg::this_grid();
  __shared__ unsigned smin[12], smax[12];
  __shared__ int so[256], sc2[256];
  __shared__ int sbase[2];
  int tid = threadIdx.x;
  int gsize = gridDim.x * blockDim.x;
  int gtid = blockIdx.x * blockDim.x + tid;

  // ---- P1: per-batch min/max ----
  if (tid < 12) { smin[tid] = 0x7F800000u; smax[tid] = 0u; }
  __syncthreads();
  for (int p = gtid; p < N; p += gsize) {
    int b = batch_of(p, offs, nb);
    for (int c = 0; c < 3; c++) {
      unsigned u = __float_as_uint(pos[p * 3 + c]);   // pos >= 0
      atomicMin(&smin[b * 3 + c], u);
      atomicMax(&smax[b * 3 + c], u);
    }
  }
  __syncthreads();
  if (tid < 3 * nb) {
    atomicMin(&gstart[tid], smin[tid]);
    atomicMax(&gstart[12 + tid], smax[tid]);
  }
  grid.sync();

  // ---- P2: lin / hist / xyz sums ----
  int m0, m1, m2;
  dims_of(gstart, nb, m0, m1, m2);
  if (gtid == 0) { gdims[0] = m0; gdims[1] = m1; gdims[2] = m2; }
  int d0 = m0 + 1, d1 = m1 + 1, d2 = m2 + 1;
  int dxyz = d0 * d1 * d2;
  int bins = nb * dxyz; if (bins > 65536) bins = 65536;
  for (int p = gtid; p < N; p += gsize) {
    int b = batch_of(p, offs, nb);
    int c0 = (int)floorf((pos[p * 3 + 0] - __uint_as_float(gstart[b * 3 + 0])) / GRID_SZ);
    int c1 = (int)floorf((pos[p * 3 + 1] - __uint_as_float(gstart[b * 3 + 1])) / GRID_SZ);
    int c2 = (int)floorf((pos[p * 3 + 2] - __uint_as_float(gstart[b * 3 + 2])) / GRID_SZ);
    int li = ((b * d0 + c0) * d1 + c1) * d2 + c2;
    if (li < 0 || li >= 65536) li = 0;
    lin[p] = li;
    atomicAdd(&hist[li], 1);
    atomicAdd(&xyzs[li * 3 + 0], pos[p * 3 + 0]);
    atomicAdd(&xyzs[li * 3 + 1], pos[p * 3 + 1]);
    atomicAdd(&xyzs[li * 3 + 2], pos[p * 3 + 2]);
  }
  grid.sync();

  // ---- P3: per-tile (256-bin) occupancy/count sums ----
  int tiles = (bins + 255) >> 8;          // <= 256
  if ((int)blockIdx.x < tiles) {
    int i = blockIdx.x * 256 + tid;
    int h = (i < bins) ? hist[i] : 0;
    int o = (h > 0), cc = h;
    for (int d = 1; d < 64; d <<= 1) { o += __shfl_xor(o, d); cc += __shfl_xor(cc, d); }
    if ((tid & 63) == 0) { so[tid >> 6] = o; sc2[tid >> 6] = cc; }
    __syncthreads();
    if (tid == 0) {
      int O = 0, C = 0;
      for (int k = 0; k < 4; k++) { O += so[k]; C += sc2[k]; }
      bsum[blockIdx.x] = make_int2(O, C);
    }
  }
  grid.sync();

  // ---- P4: per-tile scan -> rank/cursor + voxfin + offset_out ----
  if ((int)blockIdx.x < tiles) {
    int t = blockIdx.x;
    // parallel base = sum bsum[0..t)
    int2 bv = (tid < t) ? bsum[tid] : make_int2(0, 0);
    int bo = bv.x, bc = bv.y;
    for (int d = 1; d < 64; d <<= 1) { bo += __shfl_xor(bo, d); bc += __shfl_xor(bc, d); }
    if ((tid & 63) == 0) { so[tid >> 6] = bo; sc2[tid >> 6] = bc; }
    __syncthreads();
    if (tid == 0) {
      int O = 0, C = 0;
      for (int k = 0; k < 4; k++) { O += so[k]; C += sc2[k]; }
      sbase[0] = O; sbase[1] = C;
    }
    __syncthreads();
    int i = t * 256 + tid;
    int h = (i < bins) ? hist[i] : 0;
    int o = (h > 0), cc = h;
    so[tid] = o; sc2[tid] = cc;
    __syncthreads();
    for (int off = 1; off < 256; off <<= 1) {
      int vo = (tid >= off) ? so[tid - off] : 0;
      int vc = (tid >= off) ? sc2[tid - off] : 0;
      __syncthreads();
      so[tid] += vo; sc2[tid] += vc;
      __syncthreads();
    }
    if (i < bins) {
      int rk = sbase[0] + so[tid] - o;
      rank[i]   = rk;
      cursor[i] = sbase[1] + sc2[tid] - cc;
      if (h > 0) {
        float fc = (float)h;
        out_xyz[rk * 3 + 0] = xyzs[i * 3 + 0] / fc;
        out_xyz[rk * 3 + 1] = xyzs[i * 3 + 1] / fc;
        out_xyz[rk * 3 + 2] = xyzs[i * 3 + 2] / fc;
      }
      for (int tb = 0; tb < nb; tb++) {
        int idx = (tb + 1) * dxyz; if (idx > bins) idx = bins;
        if (idx < bins) { if (i == idx) out_off[tb] = (float)rk; }
        else if (i == bins - 1) out_off[tb] = (float)(sbase[0] + so[tid]);
      }
      if (i == bins - 1) rank[bins] = sbase[0] + so[tid];   // = M
    }
  }
  grid.sync();

  // ---- P5: counting-sort scatter + inv + fused f32->bf16 row move ----
  for (int p = gtid; p < N; p += gsize) {
    int li = lin[p];
    int r = rank[li];
    out_inv[p] = (float)r;
    int slot = atomicAdd(&cursor[li], 1);
    permvox[slot] = r;
    const float* src = X + (size_t)p * 128;
    short* dst = Xb + (size_t)slot * 128;
#pragma unroll
    for (int j = 0; j < 16; j++)
      *(bf16x8*)(dst + j * 8) = load_frag(src + j * 8);
  }
  grid.sync();

  // ---- P6: zero boundary-voxel featU rows ----
  int ngb = (N + 63) >> 6;
  for (int inst = blockIdx.x; inst < 2 * ngb; inst += gridDim.x) {
    int k = inst >> 1;
    int s = k * 64 + ((inst & 1) ? 63 : 0);
    if (s >= N) s = N - 1;
    int v = permvox[s];
    featU[(size_t)v * 256 + tid] = 0u;
  }
}

// ---------------- fallback (non-coop) kernels: identical to prior round ------------
__global__ void k_min(const float* __restrict__ pos, const int* __restrict__ offs,
                      int N, int nb, unsigned* gstart) {
  __shared__ unsigned smin[12], smax[12];
  int tid = threadIdx.x;
  if (tid < 12) { smin[tid] = 0x7F800000u; smax[tid] = 0u; }
  __syncthreads();
  int p = blockIdx.x * blockDim.x + tid;
  if (p < N) {
    int b = batch_of(p, offs, nb);
    for (int c = 0; c < 3; c++) {
      unsigned u = __float_as_uint(pos[p * 3 + c]);
      atomicMin(&smin[b * 3 + c], u);
      atomicMax(&smax[b * 3 + c], u);
    }
  }
  __syncthreads();
  if (tid < 3 * nb) {
    atomicMin(&gstart[tid], smin[tid]);
    atomicMax(&gstart[12 + tid], smax[tid]);
  }
}

__global__ void k_hist(const float* __restrict__ pos, const int* __restrict__ offs,
                       int N, int nb, const unsigned* gstart,
                       int* lin, int* hist, float* xyzs, int* gdims) {
  int m0, m1, m2;
  dims_of(gstart, nb, m0, m1, m2);
  int p = blockIdx.x * blockDim.x + threadIdx.x;
  if (blockIdx.x == 0 && threadIdx.x == 0) { gdims[0] = m0; gdims[1] = m1; gdims[2] = m2; }
  if (p >= N) return;
  int b = batch_of(p, offs, nb);
  int d0 = m0 + 1, d1 = m1 + 1, d2 = m2 + 1;
  int c[3];
  for (int i = 0; i < 3; i++) {
    float s = __uint_as_float(gstart[b * 3 + i]);
    c[i] = (int)floorf((pos[p * 3 + i] - s) / GRID_SZ);
  }
  int li = ((b * d0 + c[0]) * d1 + c[1]) * d2 + c[2];
  if (li < 0 || li >= 65536) li = 0;
  lin[p] = li;
  atomicAdd(&hist[li], 1);
  atomicAdd(&xyzs[li * 3 + 0], pos[p * 3 + 0]);
  atomicAdd(&xyzs[li * 3 + 1], pos[p * 3 + 1]);
  atomicAdd(&xyzs[li * 3 + 2], pos[p * 3 + 2]);
}

__global__ __launch_bounds__(1024) void k_scanA(const int* __restrict__ hist,
                                                const int* __restrict__ gdims, int nb,
                                                int2* bsum) {
  __shared__ int so[16], sc2[16];
  int d0 = gdims[0] + 1, d1 = gdims[1] + 1, d2 = gdims[2] + 1;
  int bins = nb * d0 * d1 * d2;
  if (bins > 65536) bins = 65536;
  int i = blockIdx.x * 1024 + threadIdx.x;
  int o = 0, c = 0;
  if (i < bins) { int h = hist[i]; o = (h > 0); c = h; }
  for (int d = 1; d < 64; d <<= 1) { o += __shfl_xor(o, d); c += __shfl_xor(c, d); }
  int w = threadIdx.x >> 6;
  if ((threadIdx.x & 63) == 0) { so[w] = o; sc2[w] = c; }
  __syncthreads();
  if (threadIdx.x == 0) {
    int O = 0, C = 0;
    for (int k = 0; k < 16; k++) { O += so[k]; C += sc2[k]; }
    bsum[blockIdx.x] = make_int2(O, C);
  }
}

__global__ __launch_bounds__(1024) void k_scanB(const int* __restrict__ hist,
                                                const int* __restrict__ gdims, int nb,
                                                const int2* __restrict__ bsum,
                                                int* rank, int* cursor,
                                                const float* __restrict__ xyzs,
                                                float* __restrict__ out_xyz,
                                                float* __restrict__ out_off) {
  __shared__ int so[1024], sc2[1024];
  __shared__ int sbase[2];
  int d0 = gdims[0] + 1, d1 = gdims[1] + 1, d2 = gdims[2] + 1;
  int bins = nb * d0 * d1 * d2;
  if (bins > 65536) bins = 65536;
  int b = blockIdx.x;
  int tid = threadIdx.x;
  if (tid == 0) {
    int O = 0, C = 0;
    for (int k = 0; k < b; k++) { int2 s = bsum[k]; O += s.x; C += s.y; }
    sbase[0] = O; sbase[1] = C;
  }
  int i = b * 1024 + tid;
  int h = (i < bins) ? hist[i] : 0;
  int o = (h > 0), c = h;
  so[tid] = o; sc2[tid] = c;
  __syncthreads();
  for (int off = 1; off < 1024; off <<= 1) {
    int vo = (tid >= off) ? so[tid - off] : 0;
    int vc = (tid >= off) ? sc2[tid - off] : 0;
    __syncthreads();
    so[tid] += vo; sc2[tid] += vc;
    __syncthreads();
  }
  if (i < bins) {
    int rk = sbase[0] + so[tid] - o;
    rank[i]   = rk;
    cursor[i] = sbase[1] + sc2[tid] - c;
    if (h > 0) {
      float fc = (float)h;
      out_xyz[rk * 3 + 0] = xyzs[i * 3 + 0] / fc;
      out_xyz[rk * 3 + 1] = xyzs[i * 3 + 1] / fc;
      out_xyz[rk * 3 + 2] = xyzs[i * 3 + 2] / fc;
    }
    int dxyz = d0 * d1 * d2;
    for (int t = 0; t < nb; t++) {
      int idx = (t + 1) * dxyz; if (idx > bins) idx = bins;
      if (idx < bins) { if (i == idx) out_off[t] = (float)rk; }
      else if (i == bins - 1) out_off[t] = (float)(sbase[0] + so[tid]);
    }
  }
  if (i == bins - 1) rank[bins] = sbase[0] + so[tid];   // = M
}

template <bool XBF>
__global__ void k_scatter(const int* __restrict__ lin, const int* __restrict__ rank,
                          int* cursor, int N, const float* __restrict__ X,
                          short* __restrict__ Xb, int* __restrict__ permvox,
                          float* __restrict__ out_inv) {
  int p = blockIdx.x * blockDim.x + threadIdx.x;
  if (p >= N) return;
  int li = lin[p];
  int r = rank[li];
  out_inv[p] = (float)r;
  int slot = atomicAdd(&cursor[li], 1);
  if (XBF) {
    permvox[slot] = r;
    const float* src = X + (size_t)p * 128;
    short* dst = Xb + (size_t)slot * 128;
#pragma unroll
    for (int j = 0; j < 16; j++)
      *(bf16x8*)(dst + j * 8) = load_frag(src + j * 8);
  } else {
    permvox[slot] = p;
  }
}

__global__ void k_initb(const int* __restrict__ permvox, int N,
                        unsigned* __restrict__ featU) {
  int inst = blockIdx.x;
  int k = inst >> 1;
  int s = k * 64 + ((inst & 1) ? 63 : 0);
  if (s >= N) s = N - 1;
  int v = permvox[s];
  featU[(size_t)v * 256 + threadIdx.x] = 0u;
}

// ---------------- Gram pass: T14 async pipeline, double-buffered xt ----------------
#define GCHUNK 1024
#define XTSZ (128 * 72)
__global__ __launch_bounds__(256, 2) void k_gram(const short* __restrict__ Xb, int N,
                                                 float* __restrict__ gram,
                                                 float* __restrict__ csum) {
  __shared__ short xt[2 * XTSZ];
  __shared__ float lcs[128];
  int tid = threadIdx.x;
  int wid = tid >> 6, lane = tid & 63;
  int lr = lane & 15, lg = lane >> 4;
  int base = blockIdx.x * GCHUNK;
  int cg2 = tid & 7;
  int r0 = tid >> 3;
  int r1 = (tid + 256) >> 3;
  int rsA = r0 ^ (cg2 << 3), rsB = r1 ^ (cg2 << 3);
  float cs[16];
#pragma unroll
  for (int j = 0; j < 16; j++) cs[j] = 0.f;
  f32x4 acc[2][8];
#pragma unroll
  for (int a = 0; a < 2; a++)
#pragma unroll
    for (int b = 0; b < 8; b++) acc[a][b] = (f32x4){0.f, 0.f, 0.f, 0.f};

  {
    bf16x8 a0 = {0,0,0,0,0,0,0,0}, a1 = a0, b0 = a0, b1 = a0;
    int rowA = base + r0, rowB = base + r1;
    if (rowA < N) {
      const short* s = Xb + (size_t)rowA * 128 + cg2 * 16;
      a0 = *(const bf16x8*)s; a1 = *(const bf16x8*)(s + 8);
    }
    if (rowB < N) {
      const short* s = Xb + (size_t)rowB * 128 + cg2 * 16;
      b0 = *(const bf16x8*)s; b1 = *(const bf16x8*)(s + 8);
    }
#pragma unroll
    for (int j = 0; j < 8; j++) {
      cs[j]     += __uint_as_float(((unsigned)(unsigned short)a0[j]) << 16)
                 + __uint_as_float(((unsigned)(unsigned short)b0[j]) << 16);
      cs[j + 8] += __uint_as_float(((unsigned)(unsigned short)a1[j]) << 16)
                 + __uint_as_float(((unsigned)(unsigned short)b1[j]) << 16);
    }
#pragma unroll
    for (int j = 0; j < 8; j++) {
      xt[(cg2 * 16 + j) * 72 + rsA]     = a0[j];
      xt[(cg2 * 16 + 8 + j) * 72 + rsA] = a1[j];
      xt[(cg2 * 16 + j) * 72 + rsB]     = b0[j];
      xt[(cg2 * 16 + 8 + j) * 72 + rsB] = b1[j];
    }
  }

  int nst = GCHUNK / 64;
  for (int st = 0; st < nst; st++) {
    short* cur = xt + (st & 1) * XTSZ;
    short* nxt = xt + ((st & 1) ^ 1) * XTSZ;
    __syncthreads();
    bf16x8 a0 = {0,0,0,0,0,0,0,0}, a1 = a0, b0 = a0, b1 = a0;
    bool hn = (st + 1 < nst);
    if (hn) {
      int rowA = base + (st + 1) * 64 + r0;
      int rowB = base + (st + 1) * 64 + r1;
      if (rowA < N) {
        const short* s = Xb + (size_t)rowA * 128 + cg2 * 16;
        a0 = *(const bf16x8*)s; a1 = *(const bf16x8*)(s + 8);
      }
      if (rowB < N) {
        const short* s = Xb + (size_t)rowB * 128 + cg2 * 16;
        b0 = *(const bf16x8*)s; b1 = *(const bf16x8*)(s + 8);
      }
    }
#pragma unroll
    for (int ks = 0; ks < 2; ks++) {
      int kk = ks * 32 + lg * 8;
      bf16x8 f[8], af[2];
#pragma unroll
      for (int s = 0; s < 8; s++)
        f[s] = *(const bf16x8*)(cur + (s * 16 + lr) * 72 + (kk ^ (s << 3)));
#pragma unroll
      for (int a = 0; a < 2; a++) {
        int ti = wid * 2 + a;
        af[a] = *(const bf16x8*)(cur + (ti * 16 + lr) * 72 + (kk ^ (ti << 3)));
      }
#pragma unroll
      for (int a = 0; a < 2; a++)
#pragma unroll
        for (int b = 0; b < 8; b++)
          acc[a][b] = __builtin_amdgcn_mfma_f32_16x16x32_bf16(af[a], f[b], acc[a][b], 0, 0, 0);
    }
    if (hn) {
#pragma unroll
      for (int j = 0; j < 8; j++) {
        cs[j]     += __uint_as_float(((unsigned)(unsigned short)a0[j]) << 16)
                   + __uint_as_float(((unsigned)(unsigned short)b0[j]) << 16);
        cs[j + 8] += __uint_as_float(((unsigned)(unsigned short)a1[j]) << 16)
                   + __uint_as_float(((unsigned)(unsigned short)b1[j]) << 16);
      }
#pragma unroll
      for (int j = 0; j < 8; j++) {
        nxt[(cg2 * 16 + j) * 72 + rsA]     = a0[j];
        nxt[(cg2 * 16 + 8 + j) * 72 + rsA] = a1[j];
        nxt[(cg2 * 16 + j) * 72 + rsB]     = b0[j];
        nxt[(cg2 * 16 + 8 + j) * 72 + rsB] = b1[j];
      }
    }
  }
#pragma unroll
  for (int a = 0; a < 2; a++)
#pragma unroll
    for (int b = 0; b < 8; b++)
#pragma unroll
      for (int r_ = 0; r_ < 4; r_++) {
        int ci = (wid * 2 + a) * 16 + lg * 4 + r_;
        int cj = b * 16 + lr;
        atomicAdd(&gram[ci * 128 + cj], acc[a][b][r_]);
      }
  if (tid < 128) lcs[tid] = 0.f;
  __syncthreads();
#pragma unroll
  for (int j = 0; j < 16; j++) atomicAdd(&lcs[cg2 * 16 + j], cs[j]);
  __syncthreads();
  if (tid < 128) atomicAdd(&csum[tid], lcs[tid]);
}

// ---------------- BN affine from Gram ----------------
__global__ __launch_bounds__(128) void k_finalizeG(const float* __restrict__ gram,
                                                   const float* __restrict__ csum,
                                                   const float* __restrict__ W1,
                                                   const float* __restrict__ b1,
                                                   const float* __restrict__ gamma,
                                                   const float* __restrict__ beta,
                                                   int N, float* Ac, float* Bc) {
  __shared__ float w[128], red[128], red2[128];
  int c = blockIdx.x, j = threadIdx.x;
  w[j] = W1[c * 128 + j];
  __syncthreads();
  float t = 0.f;
  for (int k = 0; k < 128; k++) t += gram[k * 128 + j] * w[k];
  red[j]  = t * w[j];
  red2[j] = w[j] * csum[j];
  __syncthreads();
  for (int off = 64; off > 0; off >>= 1) {
    if (j < off) { red[j] += red[j + off]; red2[j] += red2[j + off]; }
    __syncthreads();
  }
  if (j == 0) {
    float fn = (float)N;
    float q  = red[0] / fn;
    float md = red2[0] / fn;
    float b  = b1[c];
    float mu = md + b;
    float e2 = q + 2.f * b * md + b * b;
    float var = e2 - mu * mu;
    float s = gamma[c] * rsqrtf(var + BN_EPS);
    Ac[c] = s;
    Bc[c] = (b - mu) * s + beta[c];
  }
}

// ---------------- fallback stats (ws too small) ----------------
__global__ __launch_bounds__(256) void k_statsA(const float* __restrict__ X,
                                                const short* __restrict__ W1b,
                                                const float* __restrict__ b1, int N,
                                                float* chsum, float* chsq) {
  int tid = threadIdx.x;
  int wid = tid >> 6, lane = tid & 63;
  int lr = lane & 15, lg = lane >> 4;
  int p0 = blockIdx.x * 64;
  int wcol = wid * 64;
  f32x4 acc[4][4] = {};
  for (int kk = 0; kk < 4; kk++) {
    int k = kk * 32 + lg * 8;
    bf16x8 af[4], bfr[4];
    for (int m = 0; m < 4; m++) {
      int row = p0 + m * 16 + lr; if (row >= N) row = N - 1;
      af[m] = load_frag(X + (size_t)row * 128 + k);
    }
    for (int n = 0; n < 4; n++)
      bfr[n] = *(const bf16x8*)(W1b + (size_t)(wcol + n * 16 + lr) * 128 + k);
    for (int m = 0; m < 4; m++)
      for (int n = 0; n < 4; n++)
        acc[m][n] = __builtin_amdgcn_mfma_f32_16x16x32_bf16(af[m], bfr[n], acc[m][n], 0, 0, 0);
  }
  for (int n = 0; n < 4; n++) {
    int c = wcol + n * 16 + lr;
    float bv = b1[c];
    float s1 = 0.f, s2 = 0.f;
    for (int m = 0; m < 4; m++)
      for (int r = 0; r < 4; r++) {
        int row = p0 + m * 16 + lg * 4 + r;
        if (row < N) {
          float h = acc[m][n][r] + bv;
          s1 += h; s2 += h * h;
        }
      }
    s1 += __shfl_xor(s1, 16); s2 += __shfl_xor(s2, 16);
    s1 += __shfl_xor(s1, 32); s2 += __shfl_xor(s2, 32);
    if (lg == 0) { atomicAdd(&chsum[c], s1); atomicAdd(&chsq[c], s2); }
  }
}

__global__ void k_finalize(const float* chsum, const float* chsq, const float* b1,
                           const float* gamma, const float* beta, int N,
                           float* Ac, float* Bc) {
  int c = threadIdx.x;
  float fn = (float)N;
  float mu = chsum[c] / fn;
  float var = chsq[c] / fn - mu * mu;
  float s = gamma[c] * rsqrtf(var + BN_EPS);
  Ac[c] = s;
  Bc[c] = (b1[c] - mu) * s + beta[c];
}

// ---- fused GEMM1+BN+ReLU+GEMM2; contiguous sorted A-tile; run-aware flush ---------
template <bool XBF>
__global__ __launch_bounds__(256, 3) void k_gemmB(const float* __restrict__ X,
                                                  const short* __restrict__ Xb,
                                                  const short* __restrict__ W1b,
                                                  const short* __restrict__ W2b,
                                                  const float* __restrict__ b2,
                                                  const float* __restrict__ Ac,
                                                  const float* __restrict__ Bc,
                                                  const int* __restrict__ permvox,
                                                  const int* __restrict__ lin,
                                                  const int* __restrict__ rank,
                                                  int N, unsigned* __restrict__ featU,
                                                  int* __restrict__ bflag) {
  __shared__ char smem[64 * 264 * 2];
  __shared__ int vox_s[64];
  __shared__ int perm_s[64];
  char* axt  = smem;
  char* ylds = smem;
  unsigned short* lmax = (unsigned short*)smem;

  int tid = threadIdx.x;
  int wid = tid >> 6, lane = tid & 63;
  int lr = lane & 15, lg = lane >> 4;
  int p0 = blockIdx.x * 64;
  int wcol = wid * 64;

  if (tid < 64) {
    int s = p0 + tid;
    if (XBF) {
      vox_s[tid] = (s < N) ? permvox[s] : -1;
    } else {
      int pp = permvox[(s < N) ? s : (N - 1)];
      perm_s[tid] = pp;
      vox_s[tid] = (s < N) ? rank[lin[pp]] : -1;
    }
  }
  __syncthreads();

  {
    int row = tid >> 2, chunk = tid & 3;
    int base = row * 256 + chunk * 64;
    int sw = (row & 7) << 4;
    bf16x8 a0, a1, a2, a3;
    if (XBF) {
      int grow = p0 + row; if (grow >= N) grow = N - 1;
      const short* src = Xb + (size_t)grow * 128 + chunk * 32;
      a0 = *(const bf16x8*)(src);
      a1 = *(const bf16x8*)(src + 8);
      a2 = *(const bf16x8*)(src + 16);
      a3 = *(const bf16x8*)(src + 24);
    } else {
      int prow = perm_s[row];
      const float* src = X + (size_t)prow * 128 + chunk * 32;
      a0 = load_frag(src);
      a1 = load_frag(src + 8);
      a2 = load_frag(src + 16);
      a3 = load_frag(src + 24);
    }
    *(bf16x8*)(axt + ((base)      ^ sw)) = a0;
    *(bf16x8*)(axt + ((base + 16) ^ sw)) = a1;
    *(bf16x8*)(axt + ((base + 32) ^ sw)) = a2;
    *(bf16x8*)(axt + ((base + 48) ^ sw)) = a3;
  }
  __syncthreads();

  f32x4 acc[4][4] = {};
  for (int kk = 0; kk < 4; kk++) {
    int kbyte = kk * 64 + lg * 16;
    bf16x8 af[4], bfr[4];
    int sw = (lr & 7) << 4;
    for (int m = 0; m < 4; m++) {
      int rowA = m * 16 + lr;
      af[m] = *(const bf16x8*)(axt + ((rowA * 256 + kbyte) ^ sw));
    }
    int k = kk * 32 + lg * 8;
    for (int n = 0; n < 4; n++)
      bfr[n] = *(const bf16x8*)(W1b + (size_t)(wcol + n * 16 + lr) * 128 + k);
    for (int m = 0; m < 4; m++)
      for (int n = 0; n < 4; n++)
        acc[m][n] = __builtin_amdgcn_mfma_f32_16x16x32_bf16(af[m], bfr[n], acc[m][n], 0, 0, 0);
  }
  __syncthreads();

  for (int n = 0; n < 4; n++) {
    int c = wcol + n * 16 + lr;
    float Av = Ac[c], Bv = Bc[c];
    int colb = c * 2;
    for (int m = 0; m < 4; m++)
      for (int r = 0; r < 4; r++) {
        int row = m * 16 + lg * 4 + r;
        float y = fmaxf(acc[m][n][r] * Av + Bv, 0.0f);
        int addr = (row * 512 + colb) ^ ((row & 7) << 4);
        *(short*)(ylds + addr) = f2bf(y);
      }
  }
  __syncthreads();

  f32x4 acc2[4][4] = {};
  for (int kk = 0; kk < 8; kk++) {
    int k = kk * 32 + lg * 8;
    int kb = k * 2;
    bf16x8 af[4], bfr[4];
    for (int m = 0; m < 4; m++) {
      int row = m * 16 + lr;
      af[m] = *(const bf16x8*)(ylds + ((row * 512 + kb) ^ ((row & 7) << 4)));
    }
    for (int n = 0; n < 4; n++)
      bfr[n] = *(const bf16x8*)(W2b + (size_t)(wcol + n * 16 + lr) * 256 + k);
    for (int m = 0; m < 4; m++)
      for (int n = 0; n < 4; n++)
        acc2[m][n] = __builtin_amdgcn_mfma_f32_16x16x32_bf16(af[m], bfr[n], acc2[m][n], 0, 0, 0);
  }
  __syncthreads();

  for (int n = 0; n < 4; n++) {
    int c = wcol + n * 16 + lr;
    float bv = b2[c];
    for (int m = 0; m < 4; m++)
      for (int r = 0; r < 4; r++) {
        int row = m * 16 + lg * 4 + r;
        unsigned us = (unsigned)(unsigned short)f2bf(acc2[m][n][r] + bv);
        us = (us & 0x8000u) ? (~us & 0xFFFFu) : (us | 0x8000u);
        lmax[row * 264 + c] = (unsigned short)us;
      }
  }
  __syncthreads();

  int nrows = N - p0; if (nrows > 64) nrows = 64;
  int c = tid;
  unsigned run = 0;
  int vprev = vox_s[0];
  int run_start = 0;
  for (int row = 0; row < nrows; row++) {
    int v = vox_s[row];
    if (v != vprev) {
      size_t idx = (size_t)vprev * 256 + c;
      if (run_start > 0) {
        ((float*)featU)[idx] = dec16(run);
      } else {
        atomicMax(&featU[idx], run << 16);
        if (tid == 0) bflag[vprev] = FLAG_MAGIC;
      }
      run = 0; vprev = v; run_start = row;
    }
    run = max(run, (unsigned)lmax[row * 264 + c]);
  }
  if (vprev >= 0) {
    atomicMax(&featU[(size_t)vprev * 256 + c], run << 16);
    if (tid == 0) bflag[vprev] = FLAG_MAGIC;
  }
}

// ---------------- decode only boundary-flagged voxels ----------------
__global__ void k_decode(unsigned* featU, const int* __restrict__ bflag, size_t n) {
  size_t i = (size_t)blockIdx.x * blockDim.x + threadIdx.x;
  size_t stride = (size_t)gridDim.x * blockDim.x;
  for (; i < n; i += stride) {
    if (bflag[i >> 8] == FLAG_MAGIC) {
      unsigned e = featU[i] >> 16;
      ((float*)featU)[i] = dec16(e);
    }
  }
}

extern "C" void kernel_launch(void* const* d_in, const int* in_sizes, int n_in,
                              void* d_out, int out_size, void* d_ws, size_t ws_size,
                              hipStream_t stream) {
  const float* xyz   = (const float*)d_in[0];
  const float* X     = (const float*)d_in[1];
  const int*   offs  = (const int*)d_in[2];
  const float* W1    = (const float*)d_in[3];
  const float* b1    = (const float*)d_in[4];
  const float* gamma = (const float*)d_in[5];
  const float* beta  = (const float*)d_in[6];
  const float* W2    = (const float*)d_in[7];
  const float* b2    = (const float*)d_in[8];

  int N  = in_sizes[0] / 3;
  int nb = in_sizes[2];
  int M  = (out_size - nb - N) / 259;
  if (M <= 0) return;

  char* ws = (char*)d_ws;
  unsigned* gstart = (unsigned*)(ws + WS_START);
  int*   gdims  = (int*)(ws + WS_DIMS);
  float* chsum  = (float*)(ws + WS_CHSUM);
  float* chsq   = (float*)(ws + WS_CHSQ);
  float* Ac     = (float*)(ws + WS_AC);
  float* Bc     = (float*)(ws + WS_BC);
  short* W1b    = (short*)(ws + WS_W1B);
  short* W2b    = (short*)(ws + WS_W2B);
  float* gram   = (float*)(ws + WS_GRAM);
  float* csum   = (float*)(ws + WS_CSUM);
  int*   hist   = (int*)(ws + WS_HIST);
  int*   rank   = (int*)(ws + WS_RANK);
  int*   cursor = (int*)(ws + WS_CURS);
  int2*  bsum   = (int2*)(ws + WS_BSUM);
  float* xyzs   = (float*)(ws + WS_XYZS);
  int*   lin    = (int*)(ws + WS_LIN);
  int*   permvox = (int*)(ws + WS_PERM);
  short* Xb     = (short*)(ws + WS_XB);

  size_t req = (size_t)WS_XB + (size_t)N * 128 * 2;
  bool xbf = ws_size >= req;

  float* out_xyz  = (float*)d_out;
  float* out_feat = out_xyz + (size_t)3 * M;
  float* out_off  = out_feat + (size_t)M * 256;
  float* out_inv  = out_off + nb;
  unsigned* featU = (unsigned*)out_feat;

  int npb = (N + 255) / 256;
  int ngb = (N + 63) / 64;
  int ngr = (N + GCHUNK - 1) / GCHUNK;

  int coop = 0, dev = 0;
  hipGetDevice(&dev);
  hipDeviceGetAttribute(&coop, hipDeviceAttributeCooperativeLaunch, dev);

  hipLaunchKernelGGL(k_init, dim3(2048), dim3(256), 0, stream,
                     featU, xbf ? (size_t)0 : (size_t)M * 256, hist, xyzs,
                     chsum, chsq, gram, csum, gstart, W1, W2, W1b, W2b);

  bool coop_done = false;
  if (xbf && coop) {
    void* args[] = {(void*)&xyz, (void*)&offs, (void*)&N, (void*)&nb,
                    (void*)&gstart, (void*)&gdims, (void*)&lin, (void*)&hist,
                    (void*)&xyzs, (void*)&bsum, (void*)&rank, (void*)&cursor,
                    (void*)&X, (void*)&Xb, (void*)&permvox,
                    (void*)&out_inv, (void*)&out_xyz, (void*)&out_off, (void*)&featU};
    hipError_t e = hipLaunchCooperativeKernel((const void*)k_voxel,
                                              dim3(1024), dim3(256), args, 0, stream);
    coop_done = (e == hipSuccess);
  }

  if (!coop_done) {
    hipLaunchKernelGGL(k_min, dim3(npb), dim3(256), 0, stream, xyz, offs, N, nb, gstart);
    hipLaunchKernelGGL(k_hist, dim3(npb), dim3(256), 0, stream,
                       xyz, offs, N, nb, gstart, lin, hist, xyzs, gdims);
    hipLaunchKernelGGL(k_scanA, dim3(64), dim3(1024), 0, stream, hist, gdims, nb, bsum);
    hipLaunchKernelGGL(k_scanB, dim3(64), dim3(1024), 0, stream,
                       hist, gdims, nb, bsum, rank, cursor, xyzs, out_xyz, out_off);
    if (xbf) {
      hipLaunchKernelGGL((k_scatter<true>), dim3(npb), dim3(256), 0, stream,
                         lin, rank, cursor, N, X, Xb, permvox, out_inv);
      hipLaunchKernelGGL(k_initb, dim3(2 * ngb), dim3(256), 0, stream,
                         permvox, N, featU);
    } else {
      hipLaunchKernelGGL((k_scatter<false>), dim3(npb), dim3(256), 0, stream,
                         lin, rank, cursor, N, X, Xb, permvox, out_inv);
    }
  }

  if (xbf) {
    hipLaunchKernelGGL(k_gram, dim3(ngr), dim3(256), 0, stream, Xb, N, gram, csum);
    hipLaunchKernelGGL(k_finalizeG, dim3(256), dim3(128), 0, stream,
                       gram, csum, W1, b1, gamma, beta, N, Ac, Bc);
    hipLaunchKernelGGL((k_gemmB<true>), dim3(ngb), dim3(256), 0, stream,
                       X, Xb, W1b, W2b, b2, Ac, Bc, permvox, lin, rank, N, featU, cursor);
  } else {
    hipLaunchKernelGGL(k_statsA, dim3(ngb), dim3(256), 0, stream,
                       X, W1b, b1, N, chsum, chsq);
    hipLaunchKernelGGL(k_finalize, dim3(1), dim3(256), 0, stream,
                       chsum, chsq, b1, gamma, beta, N, Ac, Bc);
    hipLaunchKernelGGL((k_gemmB<false>), dim3(ngb), dim3(256), 0, stream,
                       X, Xb, W1b, W2b, b2, Ac, Bc, permvox, lin, rank, N, featU, cursor);
  }
  hipLaunchKernelGGL(k_decode, dim3(2048), dim3(256), 0, stream,
                     featU, cursor, (size_t)M * 256);
}

// Round 17
// 293.800 us; speedup vs baseline: 2.9342x; 2.9342x over previous
//
#include <hip/hip_runtime.h>
#include <stdint.h>

#define GRID_SZ 0.05f
#define BN_EPS 1e-5f
#define FLAG_MAGIC 0x7FECA110

typedef __attribute__((ext_vector_type(8))) short bf16x8;
typedef __attribute__((ext_vector_type(4))) float f32x4;

// ---------------- ws layout (byte offsets) ----------------
#define WS_START   0         // 24 uints: per-batch min bits / max bits
#define WS_DIMS    96        // 3 ints
#define WS_CHSUM   128       // 256 f
#define WS_CHSQ    1152
#define WS_AC      2176
#define WS_BC      3200
#define WS_W1B     4224      // 256*128 bf16 = 65536
#define WS_W2B     69760     // 256*256 bf16 = 131072
#define WS_GRAM    200832    // 128*128 f = 65536
#define WS_CSUM    266368    // 128 f = 512
#define WS_HIST    266880    // 65536 ints = 262144
#define WS_RANK    529024    // 65537 ints (+pad) = 262208
#define WS_CURS    791296    // 65536 ints = 262144 (doubles as boundary flag in gemmB)
#define WS_BSUM    1053440   // 64 int2 = 512
#define WS_XYZS    1053952   // 65536*3 f = 786432
#define WS_LIN     1840384   // N ints
#define WS_PERM    2640384   // N ints (xbf=true: vox_sorted; xbf=false: perm)
#define WS_XB      3440384   // N*128 bf16 (SORTED order when xbf=true)

__device__ __forceinline__ short f2bf(float f) {
  unsigned u = __float_as_uint(f);
  u += 0x7FFFu + ((u >> 16) & 1u);   // round-to-nearest-even
  return (short)(u >> 16);
}

__device__ __forceinline__ bf16x8 load_frag(const float* p) {
  f32x4 a = *(const f32x4*)p;
  f32x4 b = *(const f32x4*)(p + 4);
  bf16x8 r;
  r[0] = f2bf(a[0]); r[1] = f2bf(a[1]); r[2] = f2bf(a[2]); r[3] = f2bf(a[3]);
  r[4] = f2bf(b[0]); r[5] = f2bf(b[1]); r[6] = f2bf(b[2]); r[7] = f2bf(b[3]);
  return r;
}

__device__ __forceinline__ int batch_of(int p, const int* offs, int nb) {
  int b = 0;
  while (b < nb - 1 && p >= offs[b]) b++;
  return b;
}

// decode monotonic-u16 -> float
__device__ __forceinline__ float dec16(unsigned e) {
  unsigned us = (e & 0x8000u) ? (e & 0x7FFFu) : (~e & 0xFFFFu);
  return __uint_as_float(us << 16);
}

// dims (max coord per axis) from per-batch min/max corners; exact vs reference
__device__ __forceinline__ void dims_of(const unsigned* gstart, int nb,
                                        int& m0, int& m1, int& m2) {
  m0 = 0; m1 = 0; m2 = 0;
  for (int b = 0; b < nb; b++) {
    float s0 = __uint_as_float(gstart[b * 3 + 0]);
    float s1 = __uint_as_float(gstart[b * 3 + 1]);
    float s2 = __uint_as_float(gstart[b * 3 + 2]);
    float x0 = __uint_as_float(gstart[12 + b * 3 + 0]);
    float x1 = __uint_as_float(gstart[12 + b * 3 + 1]);
    float x2 = __uint_as_float(gstart[12 + b * 3 + 2]);
    m0 = max(m0, (int)floorf((x0 - s0) / GRID_SZ));
    m1 = max(m1, (int)floorf((x1 - s1) / GRID_SZ));
    m2 = max(m2, (int)floorf((x2 - s2) / GRID_SZ));
  }
}

// ---------------- init + weight conversion (fused; featN=0 in xbf path) ------------
__global__ void k_init(unsigned* featU, size_t featN, int* hist, float* xyzs,
                       float* chsum, float* chsq, float* gram, float* csum,
                       unsigned* gstart,
                       const float* __restrict__ W1, const float* __restrict__ W2,
                       short* __restrict__ W1b, short* __restrict__ W2b) {
  size_t i = (size_t)blockIdx.x * blockDim.x + threadIdx.x;
  size_t stride = (size_t)gridDim.x * blockDim.x;
  if (i < 4096) *(bf16x8*)(W1b + i * 8) = load_frag(W1 + i * 8);
  else if (i < 12288) { size_t j = i - 4096; *(bf16x8*)(W2b + j * 8) = load_frag(W2 + j * 8); }
  for (size_t j = i; j < featN; j += stride) featU[j] = 0u;
  for (size_t j = i; j < 65536; j += stride) hist[j] = 0;
  for (size_t j = i; j < 65536u * 3; j += stride) xyzs[j] = 0.f;
  for (size_t j = i; j < 16384; j += stride) gram[j] = 0.f;
  if (i < 256) { chsum[i] = 0.f; chsq[i] = 0.f; }
  if (i < 128) csum[i] = 0.f;
  if (i < 12) gstart[i] = 0x7F800000u;    // +inf bits (min half)
  else if (i < 24) gstart[i] = 0u;        // 0 bits (max half; pos >= 0)
}

// ---------------- per-batch xyz min AND max ----------------
__global__ void k_min(const float* __restrict__ pos, const int* __restrict__ offs,
                      int N, int nb, unsigned* gstart) {
  __shared__ unsigned smin[12], smax[12];
  int tid = threadIdx.x;
  if (tid < 12) { smin[tid] = 0x7F800000u; smax[tid] = 0u; }
  __syncthreads();
  int p = blockIdx.x * blockDim.x + tid;
  if (p < N) {
    int b = batch_of(p, offs, nb);
    for (int c = 0; c < 3; c++) {
      unsigned u = __float_as_uint(pos[p * 3 + c]);   // pos >= 0: uint order == float order
      atomicMin(&smin[b * 3 + c], u);
      atomicMax(&smax[b * 3 + c], u);
    }
  }
  __syncthreads();
  if (tid < 3 * nb) {
    atomicMin(&gstart[tid], smin[tid]);
    atomicMax(&gstart[12 + tid], smax[tid]);
  }
}

// ---------------- lin ids + histogram + xyz sums (dims inline) ----------------
__global__ void k_hist(const float* __restrict__ pos, const int* __restrict__ offs,
                       int N, int nb, const unsigned* gstart,
                       int* lin, int* hist, float* xyzs, int* gdims) {
  int m0, m1, m2;
  dims_of(gstart, nb, m0, m1, m2);
  int p = blockIdx.x * blockDim.x + threadIdx.x;
  if (blockIdx.x == 0 && threadIdx.x == 0) { gdims[0] = m0; gdims[1] = m1; gdims[2] = m2; }
  if (p >= N) return;
  int b = batch_of(p, offs, nb);
  int d0 = m0 + 1, d1 = m1 + 1, d2 = m2 + 1;
  int c[3];
  for (int i = 0; i < 3; i++) {
    float s = __uint_as_float(gstart[b * 3 + i]);
    c[i] = (int)floorf((pos[p * 3 + i] - s) / GRID_SZ);
  }
  int li = ((b * d0 + c[0]) * d1 + c[1]) * d2 + c[2];
  if (li < 0 || li >= 65536) li = 0;
  lin[p] = li;
  atomicAdd(&hist[li], 1);
  atomicAdd(&xyzs[li * 3 + 0], pos[p * 3 + 0]);
  atomicAdd(&xyzs[li * 3 + 1], pos[p * 3 + 1]);
  atomicAdd(&xyzs[li * 3 + 2], pos[p * 3 + 2]);
}

// ---------------- scan stage A ----------------
__global__ __launch_bounds__(1024) void k_scanA(const int* __restrict__ hist,
                                                const int* __restrict__ gdims, int nb,
                                                int2* bsum) {
  __shared__ int so[16], sc2[16];
  int d0 = gdims[0] + 1, d1 = gdims[1] + 1, d2 = gdims[2] + 1;
  int bins = nb * d0 * d1 * d2;
  if (bins > 65536) bins = 65536;
  int i = blockIdx.x * 1024 + threadIdx.x;
  int o = 0, c = 0;
  if (i < bins) { int h = hist[i]; o = (h > 0); c = h; }
  for (int d = 1; d < 64; d <<= 1) { o += __shfl_xor(o, d); c += __shfl_xor(c, d); }
  int w = threadIdx.x >> 6;
  if ((threadIdx.x & 63) == 0) { so[w] = o; sc2[w] = c; }
  __syncthreads();
  if (threadIdx.x == 0) {
    int O = 0, C = 0;
    for (int k = 0; k < 16; k++) { O += so[k]; C += sc2[k]; }
    bsum[blockIdx.x] = make_int2(O, C);
  }
}

// ---------------- scan stage B + fused voxel xyz mean + offset_out ----------------
__global__ __launch_bounds__(1024) void k_scanB(const int* __restrict__ hist,
                                                const int* __restrict__ gdims, int nb,
                                                const int2* __restrict__ bsum,
                                                int* rank, int* cursor,
                                                const float* __restrict__ xyzs,
                                                float* __restrict__ out_xyz,
                                                float* __restrict__ out_off) {
  __shared__ int so[1024], sc2[1024];
  __shared__ int sbase[2];
  int d0 = gdims[0] + 1, d1 = gdims[1] + 1, d2 = gdims[2] + 1;
  int bins = nb * d0 * d1 * d2;
  if (bins > 65536) bins = 65536;
  int b = blockIdx.x;
  int tid = threadIdx.x;
  if (tid == 0) {
    int O = 0, C = 0;
    for (int k = 0; k < b; k++) { int2 s = bsum[k]; O += s.x; C += s.y; }
    sbase[0] = O; sbase[1] = C;
  }
  int i = b * 1024 + tid;
  int h = (i < bins) ? hist[i] : 0;
  int o = (h > 0), c = h;
  so[tid] = o; sc2[tid] = c;
  __syncthreads();
  for (int off = 1; off < 1024; off <<= 1) {
    int vo = (tid >= off) ? so[tid - off] : 0;
    int vc = (tid >= off) ? sc2[tid - off] : 0;
    __syncthreads();
    so[tid] += vo; sc2[tid] += vc;
    __syncthreads();
  }
  if (i < bins) {
    int rk = sbase[0] + so[tid] - o;
    rank[i]   = rk;
    cursor[i] = sbase[1] + sc2[tid] - c;
    if (h > 0) {                          // fused voxfin
      float fc = (float)h;
      out_xyz[rk * 3 + 0] = xyzs[i * 3 + 0] / fc;
      out_xyz[rk * 3 + 1] = xyzs[i * 3 + 1] / fc;
      out_xyz[rk * 3 + 2] = xyzs[i * 3 + 2] / fc;
    }
    int dxyz = d0 * d1 * d2;
    for (int t = 0; t < nb; t++) {
      int idx = (t + 1) * dxyz; if (idx > bins) idx = bins;
      if (idx < bins) { if (i == idx) out_off[t] = (float)rk; }
      else if (i == bins - 1) out_off[t] = (float)(sbase[0] + so[tid]);
    }
  }
  if (i == bins - 1) rank[bins] = sbase[0] + so[tid];   // = M
}

// ------- counting-sort scatter + inv write + (xbf) fused f32->bf16 row move --------
template <bool XBF>
__global__ void k_scatter(const int* __restrict__ lin, const int* __restrict__ rank,
                          int* cursor, int N, const float* __restrict__ X,
                          short* __restrict__ Xb, int* __restrict__ permvox,
                          float* __restrict__ out_inv) {
  int p = blockIdx.x * blockDim.x + threadIdx.x;
  if (p >= N) return;
  int li = lin[p];
  int r = rank[li];
  out_inv[p] = (float)r;
  int slot = atomicAdd(&cursor[li], 1);
  if (XBF) {
    permvox[slot] = r;                       // vox id per sorted slot
    const float* src = X + (size_t)p * 128;
    short* dst = Xb + (size_t)slot * 128;
#pragma unroll
    for (int j = 0; j < 16; j++)
      *(bf16x8*)(dst + j * 8) = load_frag(src + j * 8);
  } else {
    permvox[slot] = p;                       // classic perm
  }
}

// ------- zero only boundary-voxel featU rows (the only atomicMax targets) ----------
__global__ void k_initb(const int* __restrict__ permvox, int N,
                        unsigned* __restrict__ featU) {
  int inst = blockIdx.x;         // 2 per 64-row tile
  int k = inst >> 1;
  int s = k * 64 + ((inst & 1) ? 63 : 0);
  if (s >= N) s = N - 1;
  int v = permvox[s];
  featU[(size_t)v * 256 + threadIdx.x] = 0u;
}

// ---------------- Gram pass: T14 async pipeline, double-buffered xt ----------------
#define GCHUNK 1024
#define XTSZ (128 * 72)
__global__ __launch_bounds__(256, 2) void k_gram(const short* __restrict__ Xb, int N,
                                                 float* __restrict__ gram,
                                                 float* __restrict__ csum) {
  __shared__ short xt[2 * XTSZ];
  __shared__ float lcs[128];
  int tid = threadIdx.x;
  int wid = tid >> 6, lane = tid & 63;
  int lr = lane & 15, lg = lane >> 4;
  int base = blockIdx.x * GCHUNK;
  int cg2 = tid & 7;
  int r0 = tid >> 3;
  int r1 = (tid + 256) >> 3;
  int rsA = r0 ^ (cg2 << 3), rsB = r1 ^ (cg2 << 3);
  float cs[16];
#pragma unroll
  for (int j = 0; j < 16; j++) cs[j] = 0.f;
  f32x4 acc[2][8];
#pragma unroll
  for (int a = 0; a < 2; a++)
#pragma unroll
    for (int b = 0; b < 8; b++) acc[a][b] = (f32x4){0.f, 0.f, 0.f, 0.f};

  {
    bf16x8 a0 = {0,0,0,0,0,0,0,0}, a1 = a0, b0 = a0, b1 = a0;
    int rowA = base + r0, rowB = base + r1;
    if (rowA < N) {
      const short* s = Xb + (size_t)rowA * 128 + cg2 * 16;
      a0 = *(const bf16x8*)s; a1 = *(const bf16x8*)(s + 8);
    }
    if (rowB < N) {
      const short* s = Xb + (size_t)rowB * 128 + cg2 * 16;
      b0 = *(const bf16x8*)s; b1 = *(const bf16x8*)(s + 8);
    }
#pragma unroll
    for (int j = 0; j < 8; j++) {
      cs[j]     += __uint_as_float(((unsigned)(unsigned short)a0[j]) << 16)
                 + __uint_as_float(((unsigned)(unsigned short)b0[j]) << 16);
      cs[j + 8] += __uint_as_float(((unsigned)(unsigned short)a1[j]) << 16)
                 + __uint_as_float(((unsigned)(unsigned short)b1[j]) << 16);
    }
#pragma unroll
    for (int j = 0; j < 8; j++) {
      xt[(cg2 * 16 + j) * 72 + rsA]     = a0[j];
      xt[(cg2 * 16 + 8 + j) * 72 + rsA] = a1[j];
      xt[(cg2 * 16 + j) * 72 + rsB]     = b0[j];
      xt[(cg2 * 16 + 8 + j) * 72 + rsB] = b1[j];
    }
  }

  int nst = GCHUNK / 64;
  for (int st = 0; st < nst; st++) {
    short* cur = xt + (st & 1) * XTSZ;
    short* nxt = xt + ((st & 1) ^ 1) * XTSZ;
    __syncthreads();
    bf16x8 a0 = {0,0,0,0,0,0,0,0}, a1 = a0, b0 = a0, b1 = a0;
    bool hn = (st + 1 < nst);
    if (hn) {
      int rowA = base + (st + 1) * 64 + r0;
      int rowB = base + (st + 1) * 64 + r1;
      if (rowA < N) {
        const short* s = Xb + (size_t)rowA * 128 + cg2 * 16;
        a0 = *(const bf16x8*)s; a1 = *(const bf16x8*)(s + 8);
      }
      if (rowB < N) {
        const short* s = Xb + (size_t)rowB * 128 + cg2 * 16;
        b0 = *(const bf16x8*)s; b1 = *(const bf16x8*)(s + 8);
      }
    }
#pragma unroll
    for (int ks = 0; ks < 2; ks++) {
      int kk = ks * 32 + lg * 8;
      bf16x8 f[8], af[2];
#pragma unroll
      for (int s = 0; s < 8; s++)
        f[s] = *(const bf16x8*)(cur + (s * 16 + lr) * 72 + (kk ^ (s << 3)));
#pragma unroll
      for (int a = 0; a < 2; a++) {
        int ti = wid * 2 + a;
        af[a] = *(const bf16x8*)(cur + (ti * 16 + lr) * 72 + (kk ^ (ti << 3)));
      }
#pragma unroll
      for (int a = 0; a < 2; a++)
#pragma unroll
        for (int b = 0; b < 8; b++)
          acc[a][b] = __builtin_amdgcn_mfma_f32_16x16x32_bf16(af[a], f[b], acc[a][b], 0, 0, 0);
    }
    if (hn) {
#pragma unroll
      for (int j = 0; j < 8; j++) {
        cs[j]     += __uint_as_float(((unsigned)(unsigned short)a0[j]) << 16)
                   + __uint_as_float(((unsigned)(unsigned short)b0[j]) << 16);
        cs[j + 8] += __uint_as_float(((unsigned)(unsigned short)a1[j]) << 16)
                   + __uint_as_float(((unsigned)(unsigned short)b1[j]) << 16);
      }
#pragma unroll
      for (int j = 0; j < 8; j++) {
        nxt[(cg2 * 16 + j) * 72 + rsA]     = a0[j];
        nxt[(cg2 * 16 + 8 + j) * 72 + rsA] = a1[j];
        nxt[(cg2 * 16 + j) * 72 + rsB]     = b0[j];
        nxt[(cg2 * 16 + 8 + j) * 72 + rsB] = b1[j];
      }
    }
  }
#pragma unroll
  for (int a = 0; a < 2; a++)
#pragma unroll
    for (int b = 0; b < 8; b++)
#pragma unroll
      for (int r_ = 0; r_ < 4; r_++) {
        int ci = (wid * 2 + a) * 16 + lg * 4 + r_;
        int cj = b * 16 + lr;
        atomicAdd(&gram[ci * 128 + cj], acc[a][b][r_]);
      }
  if (tid < 128) lcs[tid] = 0.f;
  __syncthreads();
#pragma unroll
  for (int j = 0; j < 16; j++) atomicAdd(&lcs[cg2 * 16 + j], cs[j]);
  __syncthreads();
  if (tid < 128) atomicAdd(&csum[tid], lcs[tid]);
}

// ---------------- BN affine from Gram ----------------
__global__ __launch_bounds__(128) void k_finalizeG(const float* __restrict__ gram,
                                                   const float* __restrict__ csum,
                                                   const float* __restrict__ W1,
                                                   const float* __restrict__ b1,
                                                   const float* __restrict__ gamma,
                                                   const float* __restrict__ beta,
                                                   int N, float* Ac, float* Bc) {
  __shared__ float w[128], red[128], red2[128];
  int c = blockIdx.x, j = threadIdx.x;
  w[j] = W1[c * 128 + j];
  __syncthreads();
  float t = 0.f;
  for (int k = 0; k < 128; k++) t += gram[k * 128 + j] * w[k];
  red[j]  = t * w[j];
  red2[j] = w[j] * csum[j];
  __syncthreads();
  for (int off = 64; off > 0; off >>= 1) {
    if (j < off) { red[j] += red[j + off]; red2[j] += red2[j + off]; }
    __syncthreads();
  }
  if (j == 0) {
    float fn = (float)N;
    float q  = red[0] / fn;
    float md = red2[0] / fn;
    float b  = b1[c];
    float mu = md + b;
    float e2 = q + 2.f * b * md + b * b;
    float var = e2 - mu * mu;
    float s = gamma[c] * rsqrtf(var + BN_EPS);
    Ac[c] = s;
    Bc[c] = (b - mu) * s + beta[c];
  }
}

// ---------------- fallback stats (ws too small) ----------------
__global__ __launch_bounds__(256) void k_statsA(const float* __restrict__ X,
                                                const short* __restrict__ W1b,
                                                const float* __restrict__ b1, int N,
                                                float* chsum, float* chsq) {
  int tid = threadIdx.x;
  int wid = tid >> 6, lane = tid & 63;
  int lr = lane & 15, lg = lane >> 4;
  int p0 = blockIdx.x * 64;
  int wcol = wid * 64;
  f32x4 acc[4][4] = {};
  for (int kk = 0; kk < 4; kk++) {
    int k = kk * 32 + lg * 8;
    bf16x8 af[4], bfr[4];
    for (int m = 0; m < 4; m++) {
      int row = p0 + m * 16 + lr; if (row >= N) row = N - 1;
      af[m] = load_frag(X + (size_t)row * 128 + k);
    }
    for (int n = 0; n < 4; n++)
      bfr[n] = *(const bf16x8*)(W1b + (size_t)(wcol + n * 16 + lr) * 128 + k);
    for (int m = 0; m < 4; m++)
      for (int n = 0; n < 4; n++)
        acc[m][n] = __builtin_amdgcn_mfma_f32_16x16x32_bf16(af[m], bfr[n], acc[m][n], 0, 0, 0);
  }
  for (int n = 0; n < 4; n++) {
    int c = wcol + n * 16 + lr;
    float bv = b1[c];
    float s1 = 0.f, s2 = 0.f;
    for (int m = 0; m < 4; m++)
      for (int r = 0; r < 4; r++) {
        int row = p0 + m * 16 + lg * 4 + r;
        if (row < N) {
          float h = acc[m][n][r] + bv;
          s1 += h; s2 += h * h;
        }
      }
    s1 += __shfl_xor(s1, 16); s2 += __shfl_xor(s2, 16);
    s1 += __shfl_xor(s1, 32); s2 += __shfl_xor(s2, 32);
    if (lg == 0) { atomicAdd(&chsum[c], s1); atomicAdd(&chsq[c], s2); }
  }
}

__global__ void k_finalize(const float* chsum, const float* chsq, const float* b1,
                           const float* gamma, const float* beta, int N,
                           float* Ac, float* Bc) {
  int c = threadIdx.x;
  float fn = (float)N;
  float mu = chsum[c] / fn;
  float var = chsq[c] / fn - mu * mu;
  float s = gamma[c] * rsqrtf(var + BN_EPS);
  Ac[c] = s;
  Bc[c] = (b1[c] - mu) * s + beta[c];
}

// ---- fused GEMM1+BN+ReLU+GEMM2; contiguous sorted A-tile; run-aware flush ---------
template <bool XBF>
__global__ __launch_bounds__(256, 3) void k_gemmB(const float* __restrict__ X,
                                                  const short* __restrict__ Xb,
                                                  const short* __restrict__ W1b,
                                                  const short* __restrict__ W2b,
                                                  const float* __restrict__ b2,
                                                  const float* __restrict__ Ac,
                                                  const float* __restrict__ Bc,
                                                  const int* __restrict__ permvox,
                                                  const int* __restrict__ lin,
                                                  const int* __restrict__ rank,
                                                  int N, unsigned* __restrict__ featU,
                                                  int* __restrict__ bflag) {
  __shared__ char smem[64 * 264 * 2];   // axt(16K) -> ylds(32768) -> lmax(33792), time-sliced
  __shared__ int vox_s[64];
  __shared__ int perm_s[64];
  char* axt  = smem;
  char* ylds = smem;
  unsigned short* lmax = (unsigned short*)smem;

  int tid = threadIdx.x;
  int wid = tid >> 6, lane = tid & 63;
  int lr = lane & 15, lg = lane >> 4;
  int p0 = blockIdx.x * 64;
  int wcol = wid * 64;

  if (tid < 64) {
    int s = p0 + tid;
    if (XBF) {
      vox_s[tid] = (s < N) ? permvox[s] : -1;
    } else {
      int pp = permvox[(s < N) ? s : (N - 1)];
      perm_s[tid] = pp;
      vox_s[tid] = (s < N) ? rank[lin[pp]] : -1;
    }
  }
  __syncthreads();

  // stage A-tile: thread t -> row t>>2, 64B chunk t&3
  {
    int row = tid >> 2, chunk = tid & 3;
    int base = row * 256 + chunk * 64;
    int sw = (row & 7) << 4;
    bf16x8 a0, a1, a2, a3;
    if (XBF) {
      int grow = p0 + row; if (grow >= N) grow = N - 1;
      const short* src = Xb + (size_t)grow * 128 + chunk * 32;
      a0 = *(const bf16x8*)(src);
      a1 = *(const bf16x8*)(src + 8);
      a2 = *(const bf16x8*)(src + 16);
      a3 = *(const bf16x8*)(src + 24);
    } else {
      int prow = perm_s[row];
      const float* src = X + (size_t)prow * 128 + chunk * 32;
      a0 = load_frag(src);
      a1 = load_frag(src + 8);
      a2 = load_frag(src + 16);
      a3 = load_frag(src + 24);
    }
    *(bf16x8*)(axt + ((base)      ^ sw)) = a0;
    *(bf16x8*)(axt + ((base + 16) ^ sw)) = a1;
    *(bf16x8*)(axt + ((base + 32) ^ sw)) = a2;
    *(bf16x8*)(axt + ((base + 48) ^ sw)) = a3;
  }
  __syncthreads();

  // GEMM1: h[64x256] = A(LDS) @ W1^T
  f32x4 acc[4][4] = {};
  for (int kk = 0; kk < 4; kk++) {
    int kbyte = kk * 64 + lg * 16;
    bf16x8 af[4], bfr[4];
    int sw = (lr & 7) << 4;
    for (int m = 0; m < 4; m++) {
      int rowA = m * 16 + lr;
      af[m] = *(const bf16x8*)(axt + ((rowA * 256 + kbyte) ^ sw));
    }
    int k = kk * 32 + lg * 8;
    for (int n = 0; n < 4; n++)
      bfr[n] = *(const bf16x8*)(W1b + (size_t)(wcol + n * 16 + lr) * 128 + k);
    for (int m = 0; m < 4; m++)
      for (int n = 0; n < 4; n++)
        acc[m][n] = __builtin_amdgcn_mfma_f32_16x16x32_bf16(af[m], bfr[n], acc[m][n], 0, 0, 0);
  }
  __syncthreads();

  // BN + ReLU -> swizzled bf16 in LDS
  for (int n = 0; n < 4; n++) {
    int c = wcol + n * 16 + lr;
    float Av = Ac[c], Bv = Bc[c];
    int colb = c * 2;
    for (int m = 0; m < 4; m++)
      for (int r = 0; r < 4; r++) {
        int row = m * 16 + lg * 4 + r;
        float y = fmaxf(acc[m][n][r] * Av + Bv, 0.0f);
        int addr = (row * 512 + colb) ^ ((row & 7) << 4);
        *(short*)(ylds + addr) = f2bf(y);
      }
  }
  __syncthreads();

  // GEMM2: feats[64x256] = y[64x256] @ W2^T
  f32x4 acc2[4][4] = {};
  for (int kk = 0; kk < 8; kk++) {
    int k = kk * 32 + lg * 8;
    int kb = k * 2;
    bf16x8 af[4], bfr[4];
    for (int m = 0; m < 4; m++) {
      int row = m * 16 + lr;
      af[m] = *(const bf16x8*)(ylds + ((row * 512 + kb) ^ ((row & 7) << 4)));
    }
    for (int n = 0; n < 4; n++)
      bfr[n] = *(const bf16x8*)(W2b + (size_t)(wcol + n * 16 + lr) * 256 + k);
    for (int m = 0; m < 4; m++)
      for (int n = 0; n < 4; n++)
        acc2[m][n] = __builtin_amdgcn_mfma_f32_16x16x32_bf16(af[m], bfr[n], acc2[m][n], 0, 0, 0);
  }
  __syncthreads();

  // single-shot staging: monotonic-u16 (encoded bf16); acc2 dies here
  for (int n = 0; n < 4; n++) {
    int c = wcol + n * 16 + lr;
    float bv = b2[c];
    for (int m = 0; m < 4; m++)
      for (int r = 0; r < 4; r++) {
        int row = m * 16 + lg * 4 + r;
        unsigned us = (unsigned)(unsigned short)f2bf(acc2[m][n][r] + bv);
        us = (us & 0x8000u) ? (~us & 0xFFFFu) : (us | 0x8000u);
        lmax[row * 264 + c] = (unsigned short)us;
      }
  }
  __syncthreads();

  // column pass: segmented max over voxel runs
  int nrows = N - p0; if (nrows > 64) nrows = 64;
  int c = tid;
  unsigned run = 0;
  int vprev = vox_s[0];
  int run_start = 0;
  for (int row = 0; row < nrows; row++) {
    int v = vox_s[row];
    if (v != vprev) {
      size_t idx = (size_t)vprev * 256 + c;
      if (run_start > 0) {
        ((float*)featU)[idx] = dec16(run);            // block-interior: store decoded
      } else {
        atomicMax(&featU[idx], run << 16);            // may extend previous block
        if (tid == 0) bflag[vprev] = FLAG_MAGIC;
      }
      run = 0; vprev = v; run_start = row;
    }
    run = max(run, (unsigned)lmax[row * 264 + c]);
  }
  if (vprev >= 0) {
    atomicMax(&featU[(size_t)vprev * 256 + c], run << 16);  // may extend next block
    if (tid == 0) bflag[vprev] = FLAG_MAGIC;
  }
}

// ---------------- decode only boundary-flagged voxels ----------------
__global__ void k_decode(unsigned* featU, const int* __restrict__ bflag, size_t n) {
  size_t i = (size_t)blockIdx.x * blockDim.x + threadIdx.x;
  size_t stride = (size_t)gridDim.x * blockDim.x;
  for (; i < n; i += stride) {
    if (bflag[i >> 8] == FLAG_MAGIC) {
      unsigned e = featU[i] >> 16;
      ((float*)featU)[i] = dec16(e);
    }
  }
}

extern "C" void kernel_launch(void* const* d_in, const int* in_sizes, int n_in,
                              void* d_out, int out_size, void* d_ws, size_t ws_size,
                              hipStream_t stream) {
  const float* xyz   = (const float*)d_in[0];
  const float* X     = (const float*)d_in[1];
  const int*   offs  = (const int*)d_in[2];
  const float* W1    = (const float*)d_in[3];
  const float* b1    = (const float*)d_in[4];
  const float* gamma = (const float*)d_in[5];
  const float* beta  = (const float*)d_in[6];
  const float* W2    = (const float*)d_in[7];
  const float* b2    = (const float*)d_in[8];

  int N  = in_sizes[0] / 3;
  int nb = in_sizes[2];
  int M  = (out_size - nb - N) / 259;
  if (M <= 0) return;

  char* ws = (char*)d_ws;
  unsigned* gstart = (unsigned*)(ws + WS_START);
  int*   gdims  = (int*)(ws + WS_DIMS);
  float* chsum  = (float*)(ws + WS_CHSUM);
  float* chsq   = (float*)(ws + WS_CHSQ);
  float* Ac     = (float*)(ws + WS_AC);
  float* Bc     = (float*)(ws + WS_BC);
  short* W1b    = (short*)(ws + WS_W1B);
  short* W2b    = (short*)(ws + WS_W2B);
  float* gram   = (float*)(ws + WS_GRAM);
  float* csum   = (float*)(ws + WS_CSUM);
  int*   hist   = (int*)(ws + WS_HIST);
  int*   rank   = (int*)(ws + WS_RANK);
  int*   cursor = (int*)(ws + WS_CURS);   // after k_scatter, reused as boundary flag
  int2*  bsum   = (int2*)(ws + WS_BSUM);
  float* xyzs   = (float*)(ws + WS_XYZS);
  int*   lin    = (int*)(ws + WS_LIN);
  int*   permvox = (int*)(ws + WS_PERM);  // xbf: vox per sorted slot; else perm
  short* Xb     = (short*)(ws + WS_XB);

  size_t req = (size_t)WS_XB + (size_t)N * 128 * 2;
  bool xbf = ws_size >= req;

  float* out_xyz  = (float*)d_out;
  float* out_feat = out_xyz + (size_t)3 * M;
  float* out_off  = out_feat + (size_t)M * 256;
  float* out_inv  = out_off + nb;
  unsigned* featU = (unsigned*)out_feat;

  int npb = (N + 255) / 256;
  int ngb = (N + 63) / 64;
  int ngr = (N + GCHUNK - 1) / GCHUNK;

  hipLaunchKernelGGL(k_init, dim3(2048), dim3(256), 0, stream,
                     featU, xbf ? (size_t)0 : (size_t)M * 256, hist, xyzs,
                     chsum, chsq, gram, csum, gstart, W1, W2, W1b, W2b);
  hipLaunchKernelGGL(k_min, dim3(npb), dim3(256), 0, stream, xyz, offs, N, nb, gstart);
  hipLaunchKernelGGL(k_hist, dim3(npb), dim3(256), 0, stream,
                     xyz, offs, N, nb, gstart, lin, hist, xyzs, gdims);
  hipLaunchKernelGGL(k_scanA, dim3(64), dim3(1024), 0, stream, hist, gdims, nb, bsum);
  hipLaunchKernelGGL(k_scanB, dim3(64), dim3(1024), 0, stream,
                     hist, gdims, nb, bsum, rank, cursor, xyzs, out_xyz, out_off);
  if (xbf) {
    hipLaunchKernelGGL((k_scatter<true>), dim3(npb), dim3(256), 0, stream,
                       lin, rank, cursor, N, X, Xb, permvox, out_inv);
    hipLaunchKernelGGL(k_initb, dim3(2 * ngb), dim3(256), 0, stream,
                       permvox, N, featU);
    hipLaunchKernelGGL(k_gram, dim3(ngr), dim3(256), 0, stream, Xb, N, gram, csum);
    hipLaunchKernelGGL(k_finalizeG, dim3(256), dim3(128), 0, stream,
                       gram, csum, W1, b1, gamma, beta, N, Ac, Bc);
    hipLaunchKernelGGL((k_gemmB<true>), dim3(ngb), dim3(256), 0, stream,
                       X, Xb, W1b, W2b, b2, Ac, Bc, permvox, lin, rank, N, featU, cursor);
  } else {
    hipLaunchKernelGGL((k_scatter<false>), dim3(npb), dim3(256), 0, stream,
                       lin, rank, cursor, N, X, Xb, permvox, out_inv);
    hipLaunchKernelGGL(k_statsA, dim3(ngb), dim3(256), 0, stream,
                       X, W1b, b1, N, chsum, chsq);
    hipLaunchKernelGGL(k_finalize, dim3(1), dim3(256), 0, stream,
                       chsum, chsq, b1, gamma, beta, N, Ac, Bc);
    hipLaunchKernelGGL((k_gemmB<false>), dim3(ngb), dim3(256), 0, stream,
                       X, Xb, W1b, W2b, b2, Ac, Bc, permvox, lin, rank, N, featU, cursor);
  }
  hipLaunchKernelGGL(k_decode, dim3(2048), dim3(256), 0, stream,
                     featU, cursor, (size_t)M * 256);
}

// Round 18
// 279.333 us; speedup vs baseline: 3.0862x; 1.0518x over previous
//
#include <hip/hip_runtime.h>
#include <stdint.h>

#define GRID_SZ 0.05f
#define BN_EPS 1e-5f
#define FLAG_MAGIC 0x7FECA110

typedef __attribute__((ext_vector_type(8))) short bf16x8;
typedef __attribute__((ext_vector_type(4))) float f32x4;

// ---------------- ws layout (byte offsets) ----------------
#define WS_START   0         // 24 uints: per-batch min bits / max bits
#define WS_DIMS    96        // 3 ints
#define WS_CHSUM   128       // 256 f
#define WS_CHSQ    1152
#define WS_AC      2176
#define WS_BC      3200
#define WS_W1B     4224      // 256*128 bf16 = 65536
#define WS_W2B     69760     // 256*256 bf16 = 131072
#define WS_GRAM    200832    // 128*128 f = 65536
#define WS_CSUM    266368    // 128 f = 512
#define WS_HIST    266880    // 65536 ints = 262144
#define WS_RANK    529024    // 65537 ints (+pad) = 262208
#define WS_CURS    791296    // 65536 ints = 262144 (doubles as boundary flag in gemmB)
#define WS_BSUM    1053440   // 64 int2 = 512
#define WS_XYZS    1053952   // 65536*3 f = 786432
#define WS_LIN     1840384   // N ints
#define WS_PERM    2640384   // N ints (xbf=true: vox_sorted; xbf=false: perm)
#define WS_XB      3440384   // N*128 bf16 (SORTED order when xbf=true)

__device__ __forceinline__ short f2bf(float f) {
  unsigned u = __float_as_uint(f);
  u += 0x7FFFu + ((u >> 16) & 1u);   // round-to-nearest-even
  return (short)(u >> 16);
}

__device__ __forceinline__ bf16x8 load_frag(const float* p) {
  f32x4 a = *(const f32x4*)p;
  f32x4 b = *(const f32x4*)(p + 4);
  bf16x8 r;
  r[0] = f2bf(a[0]); r[1] = f2bf(a[1]); r[2] = f2bf(a[2]); r[3] = f2bf(a[3]);
  r[4] = f2bf(b[0]); r[5] = f2bf(b[1]); r[6] = f2bf(b[2]); r[7] = f2bf(b[3]);
  return r;
}

__device__ __forceinline__ int batch_of(int p, const int* offs, int nb) {
  int b = 0;
  while (b < nb - 1 && p >= offs[b]) b++;
  return b;
}

// decode monotonic-u16 -> float
__device__ __forceinline__ float dec16(unsigned e) {
  unsigned us = (e & 0x8000u) ? (e & 0x7FFFu) : (~e & 0xFFFFu);
  return __uint_as_float(us << 16);
}

// dims (max coord per axis) from per-batch min/max corners; exact vs reference
__device__ __forceinline__ void dims_of(const unsigned* gstart, int nb,
                                        int& m0, int& m1, int& m2) {
  m0 = 0; m1 = 0; m2 = 0;
  for (int b = 0; b < nb; b++) {
    float s0 = __uint_as_float(gstart[b * 3 + 0]);
    float s1 = __uint_as_float(gstart[b * 3 + 1]);
    float s2 = __uint_as_float(gstart[b * 3 + 2]);
    float x0 = __uint_as_float(gstart[12 + b * 3 + 0]);
    float x1 = __uint_as_float(gstart[12 + b * 3 + 1]);
    float x2 = __uint_as_float(gstart[12 + b * 3 + 2]);
    m0 = max(m0, (int)floorf((x0 - s0) / GRID_SZ));
    m1 = max(m1, (int)floorf((x1 - s1) / GRID_SZ));
    m2 = max(m2, (int)floorf((x2 - s2) / GRID_SZ));
  }
}

// ---------------- init + weight conversion (fused; featN=0 in xbf path) ------------
__global__ void k_init(unsigned* featU, size_t featN, int* hist, float* xyzs,
                       float* chsum, float* chsq, float* gram, float* csum,
                       unsigned* gstart,
                       const float* __restrict__ W1, const float* __restrict__ W2,
                       short* __restrict__ W1b, short* __restrict__ W2b) {
  size_t i = (size_t)blockIdx.x * blockDim.x + threadIdx.x;
  size_t stride = (size_t)gridDim.x * blockDim.x;
  if (i < 4096) *(bf16x8*)(W1b + i * 8) = load_frag(W1 + i * 8);
  else if (i < 12288) { size_t j = i - 4096; *(bf16x8*)(W2b + j * 8) = load_frag(W2 + j * 8); }
  for (size_t j = i; j < featN; j += stride) featU[j] = 0u;
  for (size_t j = i; j < 65536; j += stride) hist[j] = 0;
  for (size_t j = i; j < 65536u * 3; j += stride) xyzs[j] = 0.f;
  for (size_t j = i; j < 16384; j += stride) gram[j] = 0.f;
  if (i < 256) { chsum[i] = 0.f; chsq[i] = 0.f; }
  if (i < 128) csum[i] = 0.f;
  if (i < 12) gstart[i] = 0x7F800000u;    // +inf bits (min half)
  else if (i < 24) gstart[i] = 0u;        // 0 bits (max half; pos >= 0)
}

// ---------------- per-batch xyz min AND max ----------------
__global__ void k_min(const float* __restrict__ pos, const int* __restrict__ offs,
                      int N, int nb, unsigned* gstart) {
  __shared__ unsigned smin[12], smax[12];
  int tid = threadIdx.x;
  if (tid < 12) { smin[tid] = 0x7F800000u; smax[tid] = 0u; }
  __syncthreads();
  int p = blockIdx.x * blockDim.x + tid;
  if (p < N) {
    int b = batch_of(p, offs, nb);
    for (int c = 0; c < 3; c++) {
      unsigned u = __float_as_uint(pos[p * 3 + c]);   // pos >= 0: uint order == float order
      atomicMin(&smin[b * 3 + c], u);
      atomicMax(&smax[b * 3 + c], u);
    }
  }
  __syncthreads();
  if (tid < 3 * nb) {
    atomicMin(&gstart[tid], smin[tid]);
    atomicMax(&gstart[12 + tid], smax[tid]);
  }
}

// ---------------- lin ids + histogram + xyz sums (dims inline) ----------------
__global__ void k_hist(const float* __restrict__ pos, const int* __restrict__ offs,
                       int N, int nb, const unsigned* gstart,
                       int* lin, int* hist, float* xyzs, int* gdims) {
  int m0, m1, m2;
  dims_of(gstart, nb, m0, m1, m2);
  int p = blockIdx.x * blockDim.x + threadIdx.x;
  if (blockIdx.x == 0 && threadIdx.x == 0) { gdims[0] = m0; gdims[1] = m1; gdims[2] = m2; }
  if (p >= N) return;
  int b = batch_of(p, offs, nb);
  int d0 = m0 + 1, d1 = m1 + 1, d2 = m2 + 1;
  int c[3];
  for (int i = 0; i < 3; i++) {
    float s = __uint_as_float(gstart[b * 3 + i]);
    c[i] = (int)floorf((pos[p * 3 + i] - s) / GRID_SZ);
  }
  int li = ((b * d0 + c[0]) * d1 + c[1]) * d2 + c[2];
  if (li < 0 || li >= 65536) li = 0;
  lin[p] = li;
  atomicAdd(&hist[li], 1);
  atomicAdd(&xyzs[li * 3 + 0], pos[p * 3 + 0]);
  atomicAdd(&xyzs[li * 3 + 1], pos[p * 3 + 1]);
  atomicAdd(&xyzs[li * 3 + 2], pos[p * 3 + 2]);
}

// ---------------- scan stage A ----------------
__global__ __launch_bounds__(1024) void k_scanA(const int* __restrict__ hist,
                                                const int* __restrict__ gdims, int nb,
                                                int2* bsum) {
  __shared__ int so[16], sc2[16];
  int d0 = gdims[0] + 1, d1 = gdims[1] + 1, d2 = gdims[2] + 1;
  int bins = nb * d0 * d1 * d2;
  if (bins > 65536) bins = 65536;
  int i = blockIdx.x * 1024 + threadIdx.x;
  int o = 0, c = 0;
  if (i < bins) { int h = hist[i]; o = (h > 0); c = h; }
  for (int d = 1; d < 64; d <<= 1) { o += __shfl_xor(o, d); c += __shfl_xor(c, d); }
  int w = threadIdx.x >> 6;
  if ((threadIdx.x & 63) == 0) { so[w] = o; sc2[w] = c; }
  __syncthreads();
  if (threadIdx.x == 0) {
    int O = 0, C = 0;
    for (int k = 0; k < 16; k++) { O += so[k]; C += sc2[k]; }
    bsum[blockIdx.x] = make_int2(O, C);
  }
}

// ---------------- scan stage B + fused voxel xyz mean + offset_out ----------------
__global__ __launch_bounds__(1024) void k_scanB(const int* __restrict__ hist,
                                                const int* __restrict__ gdims, int nb,
                                                const int2* __restrict__ bsum,
                                                int* rank, int* cursor,
                                                const float* __restrict__ xyzs,
                                                float* __restrict__ out_xyz,
                                                float* __restrict__ out_off) {
  __shared__ int so[1024], sc2[1024];
  __shared__ int sbase[2];
  int d0 = gdims[0] + 1, d1 = gdims[1] + 1, d2 = gdims[2] + 1;
  int bins = nb * d0 * d1 * d2;
  if (bins > 65536) bins = 65536;
  int b = blockIdx.x;
  int tid = threadIdx.x;
  if (tid == 0) {
    int O = 0, C = 0;
    for (int k = 0; k < b; k++) { int2 s = bsum[k]; O += s.x; C += s.y; }
    sbase[0] = O; sbase[1] = C;
  }
  int i = b * 1024 + tid;
  int h = (i < bins) ? hist[i] : 0;
  int o = (h > 0), c = h;
  so[tid] = o; sc2[tid] = c;
  __syncthreads();
  for (int off = 1; off < 1024; off <<= 1) {
    int vo = (tid >= off) ? so[tid - off] : 0;
    int vc = (tid >= off) ? sc2[tid - off] : 0;
    __syncthreads();
    so[tid] += vo; sc2[tid] += vc;
    __syncthreads();
  }
  if (i < bins) {
    int rk = sbase[0] + so[tid] - o;
    rank[i]   = rk;
    cursor[i] = sbase[1] + sc2[tid] - c;
    if (h > 0) {                          // fused voxfin
      float fc = (float)h;
      out_xyz[rk * 3 + 0] = xyzs[i * 3 + 0] / fc;
      out_xyz[rk * 3 + 1] = xyzs[i * 3 + 1] / fc;
      out_xyz[rk * 3 + 2] = xyzs[i * 3 + 2] / fc;
    }
    int dxyz = d0 * d1 * d2;
    for (int t = 0; t < nb; t++) {
      int idx = (t + 1) * dxyz; if (idx > bins) idx = bins;
      if (idx < bins) { if (i == idx) out_off[t] = (float)rk; }
      else if (i == bins - 1) out_off[t] = (float)(sbase[0] + so[tid]);
    }
  }
  if (i == bins - 1) rank[bins] = sbase[0] + so[tid];   // = M
}

// ------- counting-sort scatter + inv write + (xbf) fused f32->bf16 row move --------
template <bool XBF>
__global__ void k_scatter(const int* __restrict__ lin, const int* __restrict__ rank,
                          int* cursor, int N, const float* __restrict__ X,
                          short* __restrict__ Xb, int* __restrict__ permvox,
                          float* __restrict__ out_inv) {
  int p = blockIdx.x * blockDim.x + threadIdx.x;
  if (p >= N) return;
  int li = lin[p];
  int r = rank[li];
  out_inv[p] = (float)r;
  int slot = atomicAdd(&cursor[li], 1);
  if (XBF) {
    permvox[slot] = r;                       // vox id per sorted slot
    const float* src = X + (size_t)p * 128;
    short* dst = Xb + (size_t)slot * 128;
#pragma unroll
    for (int j = 0; j < 16; j++)
      *(bf16x8*)(dst + j * 8) = load_frag(src + j * 8);
  } else {
    permvox[slot] = p;                       // classic perm
  }
}

// ------- zero only boundary-voxel featU rows (the only atomicMax targets) ----------
__global__ void k_initb(const int* __restrict__ permvox, int N,
                        unsigned* __restrict__ featU) {
  int inst = blockIdx.x;         // 2 per 64-row tile
  int k = inst >> 1;
  int s = k * 64 + ((inst & 1) ? 63 : 0);
  if (s >= N) s = N - 1;
  int v = permvox[s];
  featU[(size_t)v * 256 + threadIdx.x] = 0u;
}

// ---------------- Gram pass: T14 async pipeline, double-buffered xt ----------------
#define GCHUNK 1024
#define XTSZ (128 * 72)
__global__ __launch_bounds__(256, 2) void k_gram(const short* __restrict__ Xb, int N,
                                                 float* __restrict__ gram,
                                                 float* __restrict__ csum) {
  __shared__ short xt[2 * XTSZ];
  __shared__ float lcs[128];
  int tid = threadIdx.x;
  int wid = tid >> 6, lane = tid & 63;
  int lr = lane & 15, lg = lane >> 4;
  int base = blockIdx.x * GCHUNK;
  int cg2 = tid & 7;
  int r0 = tid >> 3;
  int r1 = (tid + 256) >> 3;
  int rsA = r0 ^ (cg2 << 3), rsB = r1 ^ (cg2 << 3);
  float cs[16];
#pragma unroll
  for (int j = 0; j < 16; j++) cs[j] = 0.f;
  f32x4 acc[2][8];
#pragma unroll
  for (int a = 0; a < 2; a++)
#pragma unroll
    for (int b = 0; b < 8; b++) acc[a][b] = (f32x4){0.f, 0.f, 0.f, 0.f};

  {
    bf16x8 a0 = {0,0,0,0,0,0,0,0}, a1 = a0, b0 = a0, b1 = a0;
    int rowA = base + r0, rowB = base + r1;
    if (rowA < N) {
      const short* s = Xb + (size_t)rowA * 128 + cg2 * 16;
      a0 = *(const bf16x8*)s; a1 = *(const bf16x8*)(s + 8);
    }
    if (rowB < N) {
      const short* s = Xb + (size_t)rowB * 128 + cg2 * 16;
      b0 = *(const bf16x8*)s; b1 = *(const bf16x8*)(s + 8);
    }
#pragma unroll
    for (int j = 0; j < 8; j++) {
      cs[j]     += __uint_as_float(((unsigned)(unsigned short)a0[j]) << 16)
                 + __uint_as_float(((unsigned)(unsigned short)b0[j]) << 16);
      cs[j + 8] += __uint_as_float(((unsigned)(unsigned short)a1[j]) << 16)
                 + __uint_as_float(((unsigned)(unsigned short)b1[j]) << 16);
    }
#pragma unroll
    for (int j = 0; j < 8; j++) {
      xt[(cg2 * 16 + j) * 72 + rsA]     = a0[j];
      xt[(cg2 * 16 + 8 + j) * 72 + rsA] = a1[j];
      xt[(cg2 * 16 + j) * 72 + rsB]     = b0[j];
      xt[(cg2 * 16 + 8 + j) * 72 + rsB] = b1[j];
    }
  }

  int nst = GCHUNK / 64;
  for (int st = 0; st < nst; st++) {
    short* cur = xt + (st & 1) * XTSZ;
    short* nxt = xt + ((st & 1) ^ 1) * XTSZ;
    __syncthreads();
    bf16x8 a0 = {0,0,0,0,0,0,0,0}, a1 = a0, b0 = a0, b1 = a0;
    bool hn = (st + 1 < nst);
    if (hn) {
      int rowA = base + (st + 1) * 64 + r0;
      int rowB = base + (st + 1) * 64 + r1;
      if (rowA < N) {
        const short* s = Xb + (size_t)rowA * 128 + cg2 * 16;
        a0 = *(const bf16x8*)s; a1 = *(const bf16x8*)(s + 8);
      }
      if (rowB < N) {
        const short* s = Xb + (size_t)rowB * 128 + cg2 * 16;
        b0 = *(const bf16x8*)s; b1 = *(const bf16x8*)(s + 8);
      }
    }
#pragma unroll
    for (int ks = 0; ks < 2; ks++) {
      int kk = ks * 32 + lg * 8;
      bf16x8 f[8], af[2];
#pragma unroll
      for (int s = 0; s < 8; s++)
        f[s] = *(const bf16x8*)(cur + (s * 16 + lr) * 72 + (kk ^ (s << 3)));
#pragma unroll
      for (int a = 0; a < 2; a++) {
        int ti = wid * 2 + a;
        af[a] = *(const bf16x8*)(cur + (ti * 16 + lr) * 72 + (kk ^ (ti << 3)));
      }
#pragma unroll
      for (int a = 0; a < 2; a++)
#pragma unroll
        for (int b = 0; b < 8; b++)
          acc[a][b] = __builtin_amdgcn_mfma_f32_16x16x32_bf16(af[a], f[b], acc[a][b], 0, 0, 0);
    }
    if (hn) {
#pragma unroll
      for (int j = 0; j < 8; j++) {
        cs[j]     += __uint_as_float(((unsigned)(unsigned short)a0[j]) << 16)
                   + __uint_as_float(((unsigned)(unsigned short)b0[j]) << 16);
        cs[j + 8] += __uint_as_float(((unsigned)(unsigned short)a1[j]) << 16)
                   + __uint_as_float(((unsigned)(unsigned short)b1[j]) << 16);
      }
#pragma unroll
      for (int j = 0; j < 8; j++) {
        nxt[(cg2 * 16 + j) * 72 + rsA]     = a0[j];
        nxt[(cg2 * 16 + 8 + j) * 72 + rsA] = a1[j];
        nxt[(cg2 * 16 + j) * 72 + rsB]     = b0[j];
        nxt[(cg2 * 16 + 8 + j) * 72 + rsB] = b1[j];
      }
    }
  }
#pragma unroll
  for (int a = 0; a < 2; a++)
#pragma unroll
    for (int b = 0; b < 8; b++)
#pragma unroll
      for (int r_ = 0; r_ < 4; r_++) {
        int ci = (wid * 2 + a) * 16 + lg * 4 + r_;
        int cj = b * 16 + lr;
        atomicAdd(&gram[ci * 128 + cj], acc[a][b][r_]);
      }
  if (tid < 128) lcs[tid] = 0.f;
  __syncthreads();
#pragma unroll
  for (int j = 0; j < 16; j++) atomicAdd(&lcs[cg2 * 16 + j], cs[j]);
  __syncthreads();
  if (tid < 128) atomicAdd(&csum[tid], lcs[tid]);
}

// ---------------- BN affine from Gram ----------------
__global__ __launch_bounds__(128) void k_finalizeG(const float* __restrict__ gram,
                                                   const float* __restrict__ csum,
                                                   const float* __restrict__ W1,
                                                   const float* __restrict__ b1,
                                                   const float* __restrict__ gamma,
                                                   const float* __restrict__ beta,
                                                   int N, float* Ac, float* Bc) {
  __shared__ float w[128], red[128], red2[128];
  int c = blockIdx.x, j = threadIdx.x;
  w[j] = W1[c * 128 + j];
  __syncthreads();
  float t = 0.f;
  for (int k = 0; k < 128; k++) t += gram[k * 128 + j] * w[k];
  red[j]  = t * w[j];
  red2[j] = w[j] * csum[j];
  __syncthreads();
  for (int off = 64; off > 0; off >>= 1) {
    if (j < off) { red[j] += red[j + off]; red2[j] += red2[j + off]; }
    __syncthreads();
  }
  if (j == 0) {
    float fn = (float)N;
    float q  = red[0] / fn;
    float md = red2[0] / fn;
    float b  = b1[c];
    float mu = md + b;
    float e2 = q + 2.f * b * md + b * b;
    float var = e2 - mu * mu;
    float s = gamma[c] * rsqrtf(var + BN_EPS);
    Ac[c] = s;
    Bc[c] = (b - mu) * s + beta[c];
  }
}

// ---------------- fallback stats (ws too small) ----------------
__global__ __launch_bounds__(256) void k_statsA(const float* __restrict__ X,
                                                const short* __restrict__ W1b,
                                                const float* __restrict__ b1, int N,
                                                float* chsum, float* chsq) {
  int tid = threadIdx.x;
  int wid = tid >> 6, lane = tid & 63;
  int lr = lane & 15, lg = lane >> 4;
  int p0 = blockIdx.x * 64;
  int wcol = wid * 64;
  f32x4 acc[4][4] = {};
  for (int kk = 0; kk < 4; kk++) {
    int k = kk * 32 + lg * 8;
    bf16x8 af[4], bfr[4];
    for (int m = 0; m < 4; m++) {
      int row = p0 + m * 16 + lr; if (row >= N) row = N - 1;
      af[m] = load_frag(X + (size_t)row * 128 + k);
    }
    for (int n = 0; n < 4; n++)
      bfr[n] = *(const bf16x8*)(W1b + (size_t)(wcol + n * 16 + lr) * 128 + k);
    for (int m = 0; m < 4; m++)
      for (int n = 0; n < 4; n++)
        acc[m][n] = __builtin_amdgcn_mfma_f32_16x16x32_bf16(af[m], bfr[n], acc[m][n], 0, 0, 0);
  }
  for (int n = 0; n < 4; n++) {
    int c = wcol + n * 16 + lr;
    float bv = b1[c];
    float s1 = 0.f, s2 = 0.f;
    for (int m = 0; m < 4; m++)
      for (int r = 0; r < 4; r++) {
        int row = p0 + m * 16 + lg * 4 + r;
        if (row < N) {
          float h = acc[m][n][r] + bv;
          s1 += h; s2 += h * h;
        }
      }
    s1 += __shfl_xor(s1, 16); s2 += __shfl_xor(s2, 16);
    s1 += __shfl_xor(s1, 32); s2 += __shfl_xor(s2, 32);
    if (lg == 0) { atomicAdd(&chsum[c], s1); atomicAdd(&chsq[c], s2); }
  }
}

__global__ void k_finalize(const float* chsum, const float* chsq, const float* b1,
                           const float* gamma, const float* beta, int N,
                           float* Ac, float* Bc) {
  int c = threadIdx.x;
  float fn = (float)N;
  float mu = chsum[c] / fn;
  float var = chsq[c] / fn - mu * mu;
  float s = gamma[c] * rsqrtf(var + BN_EPS);
  Ac[c] = s;
  Bc[c] = (b1[c] - mu) * s + beta[c];
}

// ---- fused GEMM1+BN+ReLU+GEMM2; 512 threads / 8 waves (64x32 per wave) ------------
template <bool XBF>
__global__ __launch_bounds__(512) void k_gemmB(const float* __restrict__ X,
                                               const short* __restrict__ Xb,
                                               const short* __restrict__ W1b,
                                               const short* __restrict__ W2b,
                                               const float* __restrict__ b2,
                                               const float* __restrict__ Ac,
                                               const float* __restrict__ Bc,
                                               const int* __restrict__ permvox,
                                               const int* __restrict__ lin,
                                               const int* __restrict__ rank,
                                               int N, unsigned* __restrict__ featU,
                                               int* __restrict__ bflag) {
  __shared__ char smem[64 * 264 * 2];   // axt(16K) -> ylds(32768) -> lmax(33792), time-sliced
  __shared__ int vox_s[64];
  __shared__ int perm_s[64];
  char* axt  = smem;                    // [64][128] bf16 row-major, byte ^ ((row&7)<<4)
  char* ylds = smem;
  unsigned short* lmax = (unsigned short*)smem;   // row-major [64][264] monotonic-u16

  int tid = threadIdx.x;
  int wid = tid >> 6, lane = tid & 63;
  int lr = lane & 15, lg = lane >> 4;
  int p0 = blockIdx.x * 64;
  int wcol = wid * 32;                  // 8 waves x 32 cols

  if (tid < 64) {
    int s = p0 + tid;
    if (XBF) {
      vox_s[tid] = (s < N) ? permvox[s] : -1;
    } else {
      int pp = permvox[(s < N) ? s : (N - 1)];
      perm_s[tid] = pp;
      vox_s[tid] = (s < N) ? rank[lin[pp]] : -1;
    }
  }
  __syncthreads();

  // stage A-tile: thread t -> row t>>3, 32B chunk t&7 (coalesced 256B per row)
  {
    int row = tid >> 3, chunk = tid & 7;
    int base = row * 256 + chunk * 32;
    int sw = (row & 7) << 4;
    bf16x8 a0, a1;
    if (XBF) {
      int grow = p0 + row; if (grow >= N) grow = N - 1;
      const short* src = Xb + (size_t)grow * 128 + chunk * 16;
      a0 = *(const bf16x8*)(src);
      a1 = *(const bf16x8*)(src + 8);
    } else {
      int prow = perm_s[row];
      const float* src = X + (size_t)prow * 128 + chunk * 16;
      a0 = load_frag(src);
      a1 = load_frag(src + 8);
    }
    *(bf16x8*)(axt + ((base)      ^ sw)) = a0;
    *(bf16x8*)(axt + ((base + 16) ^ sw)) = a1;
  }
  __syncthreads();

  // GEMM1: each wave computes h[64 x 32] slice = A(LDS) @ W1^T[:, wcol..wcol+31]
  f32x4 acc[4][2] = {};
  for (int kk = 0; kk < 4; kk++) {
    int kbyte = kk * 64 + lg * 16;
    bf16x8 af[4], bfr[2];
    int sw = (lr & 7) << 4;
    for (int m = 0; m < 4; m++) {
      int rowA = m * 16 + lr;
      af[m] = *(const bf16x8*)(axt + ((rowA * 256 + kbyte) ^ sw));
    }
    int k = kk * 32 + lg * 8;
    for (int n = 0; n < 2; n++)
      bfr[n] = *(const bf16x8*)(W1b + (size_t)(wcol + n * 16 + lr) * 128 + k);
    for (int m = 0; m < 4; m++)
      for (int n = 0; n < 2; n++)
        acc[m][n] = __builtin_amdgcn_mfma_f32_16x16x32_bf16(af[m], bfr[n], acc[m][n], 0, 0, 0);
  }
  __syncthreads();   // axt reads done before ylds overwrites

  // BN + ReLU -> swizzled bf16 in LDS (each wave writes its 32 columns)
  for (int n = 0; n < 2; n++) {
    int c = wcol + n * 16 + lr;
    float Av = Ac[c], Bv = Bc[c];
    int colb = c * 2;
    for (int m = 0; m < 4; m++)
      for (int r = 0; r < 4; r++) {
        int row = m * 16 + lg * 4 + r;
        float y = fmaxf(acc[m][n][r] * Av + Bv, 0.0f);
        int addr = (row * 512 + colb) ^ ((row & 7) << 4);
        *(short*)(ylds + addr) = f2bf(y);
      }
  }
  __syncthreads();

  // GEMM2: feats[64 x 32 slice] = y[64x256] @ W2^T[:, wcol..wcol+31]
  f32x4 acc2[4][2] = {};
  for (int kk = 0; kk < 8; kk++) {
    int k = kk * 32 + lg * 8;
    int kb = k * 2;
    bf16x8 af[4], bfr[2];
    for (int m = 0; m < 4; m++) {
      int row = m * 16 + lr;
      af[m] = *(const bf16x8*)(ylds + ((row * 512 + kb) ^ ((row & 7) << 4)));
    }
    for (int n = 0; n < 2; n++)
      bfr[n] = *(const bf16x8*)(W2b + (size_t)(wcol + n * 16 + lr) * 256 + k);
    for (int m = 0; m < 4; m++)
      for (int n = 0; n < 2; n++)
        acc2[m][n] = __builtin_amdgcn_mfma_f32_16x16x32_bf16(af[m], bfr[n], acc2[m][n], 0, 0, 0);
  }
  __syncthreads();   // all ylds reads complete before overwrite

  // single-shot staging: monotonic-u16 (encoded bf16); acc2 dies here
  for (int n = 0; n < 2; n++) {
    int c = wcol + n * 16 + lr;
    float bv = b2[c];
    for (int m = 0; m < 4; m++)
      for (int r = 0; r < 4; r++) {
        int row = m * 16 + lg * 4 + r;
        unsigned us = (unsigned)(unsigned short)f2bf(acc2[m][n][r] + bv);
        us = (us & 0x8000u) ? (~us & 0xFFFFu) : (us | 0x8000u);
        lmax[row * 264 + c] = (unsigned short)us;
      }
  }
  __syncthreads();

  // column pass on waves 0-3 (c = tid); waves 4-7 exit
  if (tid < 256) {
    int nrows = N - p0; if (nrows > 64) nrows = 64;
    int c = tid;
    unsigned run = 0;
    int vprev = vox_s[0];
    int run_start = 0;
    for (int row = 0; row < nrows; row++) {
      int v = vox_s[row];
      if (v != vprev) {
        size_t idx = (size_t)vprev * 256 + c;
        if (run_start > 0) {
          ((float*)featU)[idx] = dec16(run);            // block-interior: store decoded
        } else {
          atomicMax(&featU[idx], run << 16);            // may extend previous block
          if (tid == 0) bflag[vprev] = FLAG_MAGIC;
        }
        run = 0; vprev = v; run_start = row;
      }
      run = max(run, (unsigned)lmax[row * 264 + c]);
    }
    if (vprev >= 0) {
      atomicMax(&featU[(size_t)vprev * 256 + c], run << 16);  // may extend next block
      if (tid == 0) bflag[vprev] = FLAG_MAGIC;
    }
  }
}

// ---------------- decode only boundary-flagged voxels ----------------
__global__ void k_decode(unsigned* featU, const int* __restrict__ bflag, size_t n) {
  size_t i = (size_t)blockIdx.x * blockDim.x + threadIdx.x;
  size_t stride = (size_t)gridDim.x * blockDim.x;
  for (; i < n; i += stride) {
    if (bflag[i >> 8] == FLAG_MAGIC) {
      unsigned e = featU[i] >> 16;
      ((float*)featU)[i] = dec16(e);
    }
  }
}

extern "C" void kernel_launch(void* const* d_in, const int* in_sizes, int n_in,
                              void* d_out, int out_size, void* d_ws, size_t ws_size,
                              hipStream_t stream) {
  const float* xyz   = (const float*)d_in[0];
  const float* X     = (const float*)d_in[1];
  const int*   offs  = (const int*)d_in[2];
  const float* W1    = (const float*)d_in[3];
  const float* b1    = (const float*)d_in[4];
  const float* gamma = (const float*)d_in[5];
  const float* beta  = (const float*)d_in[6];
  const float* W2    = (const float*)d_in[7];
  const float* b2    = (const float*)d_in[8];

  int N  = in_sizes[0] / 3;
  int nb = in_sizes[2];
  int M  = (out_size - nb - N) / 259;
  if (M <= 0) return;

  char* ws = (char*)d_ws;
  unsigned* gstart = (unsigned*)(ws + WS_START);
  int*   gdims  = (int*)(ws + WS_DIMS);
  float* chsum  = (float*)(ws + WS_CHSUM);
  float* chsq   = (float*)(ws + WS_CHSQ);
  float* Ac     = (float*)(ws + WS_AC);
  float* Bc     = (float*)(ws + WS_BC);
  short* W1b    = (short*)(ws + WS_W1B);
  short* W2b    = (short*)(ws + WS_W2B);
  float* gram   = (float*)(ws + WS_GRAM);
  float* csum   = (float*)(ws + WS_CSUM);
  int*   hist   = (int*)(ws + WS_HIST);
  int*   rank   = (int*)(ws + WS_RANK);
  int*   cursor = (int*)(ws + WS_CURS);   // after k_scatter, reused as boundary flag
  int2*  bsum   = (int2*)(ws + WS_BSUM);
  float* xyzs   = (float*)(ws + WS_XYZS);
  int*   lin    = (int*)(ws + WS_LIN);
  int*   permvox = (int*)(ws + WS_PERM);  // xbf: vox per sorted slot; else perm
  short* Xb     = (short*)(ws + WS_XB);

  size_t req = (size_t)WS_XB + (size_t)N * 128 * 2;
  bool xbf = ws_size >= req;

  float* out_xyz  = (float*)d_out;
  float* out_feat = out_xyz + (size_t)3 * M;
  float* out_off  = out_feat + (size_t)M * 256;
  float* out_inv  = out_off + nb;
  unsigned* featU = (unsigned*)out_feat;

  int npb = (N + 255) / 256;
  int ngb = (N + 63) / 64;
  int ngr = (N + GCHUNK - 1) / GCHUNK;

  hipLaunchKernelGGL(k_init, dim3(2048), dim3(256), 0, stream,
                     featU, xbf ? (size_t)0 : (size_t)M * 256, hist, xyzs,
                     chsum, chsq, gram, csum, gstart, W1, W2, W1b, W2b);
  hipLaunchKernelGGL(k_min, dim3(npb), dim3(256), 0, stream, xyz, offs, N, nb, gstart);
  hipLaunchKernelGGL(k_hist, dim3(npb), dim3(256), 0, stream,
                     xyz, offs, N, nb, gstart, lin, hist, xyzs, gdims);
  hipLaunchKernelGGL(k_scanA, dim3(64), dim3(1024), 0, stream, hist, gdims, nb, bsum);
  hipLaunchKernelGGL(k_scanB, dim3(64), dim3(1024), 0, stream,
                     hist, gdims, nb, bsum, rank, cursor, xyzs, out_xyz, out_off);
  if (xbf) {
    hipLaunchKernelGGL((k_scatter<true>), dim3(npb), dim3(256), 0, stream,
                       lin, rank, cursor, N, X, Xb, permvox, out_inv);
    hipLaunchKernelGGL(k_initb, dim3(2 * ngb), dim3(256), 0, stream,
                       permvox, N, featU);
    hipLaunchKernelGGL(k_gram, dim3(ngr), dim3(256), 0, stream, Xb, N, gram, csum);
    hipLaunchKernelGGL(k_finalizeG, dim3(256), dim3(128), 0, stream,
                       gram, csum, W1, b1, gamma, beta, N, Ac, Bc);
    hipLaunchKernelGGL((k_gemmB<true>), dim3(ngb), dim3(512), 0, stream,
                       X, Xb, W1b, W2b, b2, Ac, Bc, permvox, lin, rank, N, featU, cursor);
  } else {
    hipLaunchKernelGGL((k_scatter<false>), dim3(npb), dim3(256), 0, stream,
                       lin, rank, cursor, N, X, Xb, permvox, out_inv);
    hipLaunchKernelGGL(k_statsA, dim3(ngb), dim3(256), 0, stream,
                       X, W1b, b1, N, chsum, chsq);
    hipLaunchKernelGGL(k_finalize, dim3(1), dim3(256), 0, stream,
                       chsum, chsq, b1, gamma, beta, N, Ac, Bc);
    hipLaunchKernelGGL((k_gemmB<false>), dim3(ngb), dim3(512), 0, stream,
                       X, Xb, W1b, W2b, b2, Ac, Bc, permvox, lin, rank, N, featU, cursor);
  }
  hipLaunchKernelGGL(k_decode, dim3(2048), dim3(256), 0, stream,
                     featU, cursor, (size_t)M * 256);
}

// Round 19
// 277.365 us; speedup vs baseline: 3.1081x; 1.0071x over previous
//
#include <hip/hip_runtime.h>
#include <stdint.h>

#define GRID_SZ 0.05f
#define BN_EPS 1e-5f
#define FLAG_MAGIC 0x7FECA110

typedef __attribute__((ext_vector_type(8))) short bf16x8;
typedef __attribute__((ext_vector_type(4))) float f32x4;

// ---------------- ws layout (byte offsets) ----------------
#define WS_START   0         // 24 uints: per-batch min bits / max bits
#define WS_DIMS    96        // 3 ints
#define WS_CHSUM   128       // 256 f
#define WS_CHSQ    1152
#define WS_AC      2176
#define WS_BC      3200
#define WS_W1B     4224      // 256*128 bf16 = 65536
#define WS_W2B     69760     // 256*256 bf16 = 131072
#define WS_GRAM    200832    // 128*128 f = 65536
#define WS_CSUM    266368    // 128 f = 512
#define WS_HIST    266880    // 65536 ints = 262144
#define WS_RANK    529024    // 65537 ints (+pad) = 262208
#define WS_CURS    791296    // 65536 ints = 262144 (doubles as boundary flag in gemmB)
#define WS_BSUM    1053440   // 64 int2 = 512
#define WS_XYZS    1053952   // 65536*3 f = 786432
#define WS_LIN     1840384   // N ints
#define WS_PERM    2640384   // N ints (xbf=true: vox_sorted; xbf=false: perm)
#define WS_XB      3440384   // N*128 bf16 (SORTED order when xbf=true)

__device__ __forceinline__ short f2bf(float f) {
  unsigned u = __float_as_uint(f);
  u += 0x7FFFu + ((u >> 16) & 1u);   // round-to-nearest-even
  return (short)(u >> 16);
}

__device__ __forceinline__ bf16x8 load_frag(const float* p) {
  f32x4 a = *(const f32x4*)p;
  f32x4 b = *(const f32x4*)(p + 4);
  bf16x8 r;
  r[0] = f2bf(a[0]); r[1] = f2bf(a[1]); r[2] = f2bf(a[2]); r[3] = f2bf(a[3]);
  r[4] = f2bf(b[0]); r[5] = f2bf(b[1]); r[6] = f2bf(b[2]); r[7] = f2bf(b[3]);
  return r;
}

__device__ __forceinline__ int batch_of(int p, const int* offs, int nb) {
  int b = 0;
  while (b < nb - 1 && p >= offs[b]) b++;
  return b;
}

// decode monotonic-u16 -> float
__device__ __forceinline__ float dec16(unsigned e) {
  unsigned us = (e & 0x8000u) ? (e & 0x7FFFu) : (~e & 0xFFFFu);
  return __uint_as_float(us << 16);
}

// dims (max coord per axis) from per-batch min/max corners; exact vs reference
__device__ __forceinline__ void dims_of(const unsigned* gstart, int nb,
                                        int& m0, int& m1, int& m2) {
  m0 = 0; m1 = 0; m2 = 0;
  for (int b = 0; b < nb; b++) {
    float s0 = __uint_as_float(gstart[b * 3 + 0]);
    float s1 = __uint_as_float(gstart[b * 3 + 1]);
    float s2 = __uint_as_float(gstart[b * 3 + 2]);
    float x0 = __uint_as_float(gstart[12 + b * 3 + 0]);
    float x1 = __uint_as_float(gstart[12 + b * 3 + 1]);
    float x2 = __uint_as_float(gstart[12 + b * 3 + 2]);
    m0 = max(m0, (int)floorf((x0 - s0) / GRID_SZ));
    m1 = max(m1, (int)floorf((x1 - s1) / GRID_SZ));
    m2 = max(m2, (int)floorf((x2 - s2) / GRID_SZ));
  }
}

// ---------------- init + weight conversion (fused; featN=0 in xbf path) ------------
__global__ void k_init(unsigned* featU, size_t featN, int* hist, float* xyzs,
                       float* chsum, float* chsq, float* gram, float* csum,
                       unsigned* gstart,
                       const float* __restrict__ W1, const float* __restrict__ W2,
                       short* __restrict__ W1b, short* __restrict__ W2b) {
  size_t i = (size_t)blockIdx.x * blockDim.x + threadIdx.x;
  size_t stride = (size_t)gridDim.x * blockDim.x;
  if (i < 4096) *(bf16x8*)(W1b + i * 8) = load_frag(W1 + i * 8);
  else if (i < 12288) { size_t j = i - 4096; *(bf16x8*)(W2b + j * 8) = load_frag(W2 + j * 8); }
  for (size_t j = i; j < featN; j += stride) featU[j] = 0u;
  for (size_t j = i; j < 65536; j += stride) hist[j] = 0;
  for (size_t j = i; j < 65536u * 3; j += stride) xyzs[j] = 0.f;
  for (size_t j = i; j < 16384; j += stride) gram[j] = 0.f;
  if (i < 256) { chsum[i] = 0.f; chsq[i] = 0.f; }
  if (i < 128) csum[i] = 0.f;
  if (i < 12) gstart[i] = 0x7F800000u;    // +inf bits (min half)
  else if (i < 24) gstart[i] = 0u;        // 0 bits (max half; pos >= 0)
}

// ---------------- per-batch xyz min AND max ----------------
__global__ void k_min(const float* __restrict__ pos, const int* __restrict__ offs,
                      int N, int nb, unsigned* gstart) {
  __shared__ unsigned smin[12], smax[12];
  int tid = threadIdx.x;
  if (tid < 12) { smin[tid] = 0x7F800000u; smax[tid] = 0u; }
  __syncthreads();
  int p = blockIdx.x * blockDim.x + tid;
  if (p < N) {
    int b = batch_of(p, offs, nb);
    for (int c = 0; c < 3; c++) {
      unsigned u = __float_as_uint(pos[p * 3 + c]);   // pos >= 0: uint order == float order
      atomicMin(&smin[b * 3 + c], u);
      atomicMax(&smax[b * 3 + c], u);
    }
  }
  __syncthreads();
  if (tid < 3 * nb) {
    atomicMin(&gstart[tid], smin[tid]);
    atomicMax(&gstart[12 + tid], smax[tid]);
  }
}

// ---------------- lin ids + histogram + xyz sums (dims inline) ----------------
__global__ void k_hist(const float* __restrict__ pos, const int* __restrict__ offs,
                       int N, int nb, const unsigned* gstart,
                       int* lin, int* hist, float* xyzs, int* gdims) {
  int m0, m1, m2;
  dims_of(gstart, nb, m0, m1, m2);
  int p = blockIdx.x * blockDim.x + threadIdx.x;
  if (blockIdx.x == 0 && threadIdx.x == 0) { gdims[0] = m0; gdims[1] = m1; gdims[2] = m2; }
  if (p >= N) return;
  int b = batch_of(p, offs, nb);
  int d0 = m0 + 1, d1 = m1 + 1, d2 = m2 + 1;
  int c[3];
  for (int i = 0; i < 3; i++) {
    float s = __uint_as_float(gstart[b * 3 + i]);
    c[i] = (int)floorf((pos[p * 3 + i] - s) / GRID_SZ);
  }
  int li = ((b * d0 + c[0]) * d1 + c[1]) * d2 + c[2];
  if (li < 0 || li >= 65536) li = 0;
  lin[p] = li;
  atomicAdd(&hist[li], 1);
  atomicAdd(&xyzs[li * 3 + 0], pos[p * 3 + 0]);
  atomicAdd(&xyzs[li * 3 + 1], pos[p * 3 + 1]);
  atomicAdd(&xyzs[li * 3 + 2], pos[p * 3 + 2]);
}

// ---------------- scan stage A ----------------
__global__ __launch_bounds__(1024) void k_scanA(const int* __restrict__ hist,
                                                const int* __restrict__ gdims, int nb,
                                                int2* bsum) {
  __shared__ int so[16], sc2[16];
  int d0 = gdims[0] + 1, d1 = gdims[1] + 1, d2 = gdims[2] + 1;
  int bins = nb * d0 * d1 * d2;
  if (bins > 65536) bins = 65536;
  int i = blockIdx.x * 1024 + threadIdx.x;
  int o = 0, c = 0;
  if (i < bins) { int h = hist[i]; o = (h > 0); c = h; }
  for (int d = 1; d < 64; d <<= 1) { o += __shfl_xor(o, d); c += __shfl_xor(c, d); }
  int w = threadIdx.x >> 6;
  if ((threadIdx.x & 63) == 0) { so[w] = o; sc2[w] = c; }
  __syncthreads();
  if (threadIdx.x == 0) {
    int O = 0, C = 0;
    for (int k = 0; k < 16; k++) { O += so[k]; C += sc2[k]; }
    bsum[blockIdx.x] = make_int2(O, C);
  }
}

// ---------------- scan stage B + fused voxel xyz mean + offset_out ----------------
__global__ __launch_bounds__(1024) void k_scanB(const int* __restrict__ hist,
                                                const int* __restrict__ gdims, int nb,
                                                const int2* __restrict__ bsum,
                                                int* rank, int* cursor,
                                                const float* __restrict__ xyzs,
                                                float* __restrict__ out_xyz,
                                                float* __restrict__ out_off) {
  __shared__ int so[1024], sc2[1024];
  __shared__ int sbase[2];
  int d0 = gdims[0] + 1, d1 = gdims[1] + 1, d2 = gdims[2] + 1;
  int bins = nb * d0 * d1 * d2;
  if (bins > 65536) bins = 65536;
  int b = blockIdx.x;
  int tid = threadIdx.x;
  if (tid == 0) {
    int O = 0, C = 0;
    for (int k = 0; k < b; k++) { int2 s = bsum[k]; O += s.x; C += s.y; }
    sbase[0] = O; sbase[1] = C;
  }
  int i = b * 1024 + tid;
  int h = (i < bins) ? hist[i] : 0;
  int o = (h > 0), c = h;
  so[tid] = o; sc2[tid] = c;
  __syncthreads();
  for (int off = 1; off < 1024; off <<= 1) {
    int vo = (tid >= off) ? so[tid - off] : 0;
    int vc = (tid >= off) ? sc2[tid - off] : 0;
    __syncthreads();
    so[tid] += vo; sc2[tid] += vc;
    __syncthreads();
  }
  if (i < bins) {
    int rk = sbase[0] + so[tid] - o;
    rank[i]   = rk;
    cursor[i] = sbase[1] + sc2[tid] - c;
    if (h > 0) {                          // fused voxfin
      float fc = (float)h;
      out_xyz[rk * 3 + 0] = xyzs[i * 3 + 0] / fc;
      out_xyz[rk * 3 + 1] = xyzs[i * 3 + 1] / fc;
      out_xyz[rk * 3 + 2] = xyzs[i * 3 + 2] / fc;
    }
    int dxyz = d0 * d1 * d2;
    for (int t = 0; t < nb; t++) {
      int idx = (t + 1) * dxyz; if (idx > bins) idx = bins;
      if (idx < bins) { if (i == idx) out_off[t] = (float)rk; }
      else if (i == bins - 1) out_off[t] = (float)(sbase[0] + so[tid]);
    }
  }
  if (i == bins - 1) rank[bins] = sbase[0] + so[tid];   // = M
}

// ------- counting-sort scatter + inv write + (xbf) fused f32->bf16 row move --------
template <bool XBF>
__global__ void k_scatter(const int* __restrict__ lin, const int* __restrict__ rank,
                          int* cursor, int N, const float* __restrict__ X,
                          short* __restrict__ Xb, int* __restrict__ permvox,
                          float* __restrict__ out_inv) {
  int p = blockIdx.x * blockDim.x + threadIdx.x;
  if (p >= N) return;
  int li = lin[p];
  int r = rank[li];
  out_inv[p] = (float)r;
  int slot = atomicAdd(&cursor[li], 1);
  if (XBF) {
    permvox[slot] = r;                       // vox id per sorted slot
    const float* src = X + (size_t)p * 128;
    short* dst = Xb + (size_t)slot * 128;
#pragma unroll
    for (int j = 0; j < 16; j++)
      *(bf16x8*)(dst + j * 8) = load_frag(src + j * 8);
  } else {
    permvox[slot] = p;                       // classic perm
  }
}

// ------- zero only boundary-voxel featU rows (the only atomicMax targets) ----------
__global__ void k_initb(const int* __restrict__ permvox, int N,
                        unsigned* __restrict__ featU) {
  int inst = blockIdx.x;         // 2 per 64-row tile
  int k = inst >> 1;
  int s = k * 64 + ((inst & 1) ? 63 : 0);
  if (s >= N) s = N - 1;
  int v = permvox[s];
  featU[(size_t)v * 256 + threadIdx.x] = 0u;
}

// ---------------- Gram pass: T14 async pipeline, double-buffered xt ----------------
#define GCHUNK 1024
#define XTSZ (128 * 72)
__global__ __launch_bounds__(256, 2) void k_gram(const short* __restrict__ Xb, int N,
                                                 float* __restrict__ gram,
                                                 float* __restrict__ csum) {
  __shared__ short xt[2 * XTSZ];
  __shared__ float lcs[128];
  int tid = threadIdx.x;
  int wid = tid >> 6, lane = tid & 63;
  int lr = lane & 15, lg = lane >> 4;
  int base = blockIdx.x * GCHUNK;
  int cg2 = tid & 7;
  int r0 = tid >> 3;
  int r1 = (tid + 256) >> 3;
  int rsA = r0 ^ (cg2 << 3), rsB = r1 ^ (cg2 << 3);
  float cs[16];
#pragma unroll
  for (int j = 0; j < 16; j++) cs[j] = 0.f;
  f32x4 acc[2][8];
#pragma unroll
  for (int a = 0; a < 2; a++)
#pragma unroll
    for (int b = 0; b < 8; b++) acc[a][b] = (f32x4){0.f, 0.f, 0.f, 0.f};

  {
    bf16x8 a0 = {0,0,0,0,0,0,0,0}, a1 = a0, b0 = a0, b1 = a0;
    int rowA = base + r0, rowB = base + r1;
    if (rowA < N) {
      const short* s = Xb + (size_t)rowA * 128 + cg2 * 16;
      a0 = *(const bf16x8*)s; a1 = *(const bf16x8*)(s + 8);
    }
    if (rowB < N) {
      const short* s = Xb + (size_t)rowB * 128 + cg2 * 16;
      b0 = *(const bf16x8*)s; b1 = *(const bf16x8*)(s + 8);
    }
#pragma unroll
    for (int j = 0; j < 8; j++) {
      cs[j]     += __uint_as_float(((unsigned)(unsigned short)a0[j]) << 16)
                 + __uint_as_float(((unsigned)(unsigned short)b0[j]) << 16);
      cs[j + 8] += __uint_as_float(((unsigned)(unsigned short)a1[j]) << 16)
                 + __uint_as_float(((unsigned)(unsigned short)b1[j]) << 16);
    }
#pragma unroll
    for (int j = 0; j < 8; j++) {
      xt[(cg2 * 16 + j) * 72 + rsA]     = a0[j];
      xt[(cg2 * 16 + 8 + j) * 72 + rsA] = a1[j];
      xt[(cg2 * 16 + j) * 72 + rsB]     = b0[j];
      xt[(cg2 * 16 + 8 + j) * 72 + rsB] = b1[j];
    }
  }

  int nst = GCHUNK / 64;
  for (int st = 0; st < nst; st++) {
    short* cur = xt + (st & 1) * XTSZ;
    short* nxt = xt + ((st & 1) ^ 1) * XTSZ;
    __syncthreads();
    bf16x8 a0 = {0,0,0,0,0,0,0,0}, a1 = a0, b0 = a0, b1 = a0;
    bool hn = (st + 1 < nst);
    if (hn) {
      int rowA = base + (st + 1) * 64 + r0;
      int rowB = base + (st + 1) * 64 + r1;
      if (rowA < N) {
        const short* s = Xb + (size_t)rowA * 128 + cg2 * 16;
        a0 = *(const bf16x8*)s; a1 = *(const bf16x8*)(s + 8);
      }
      if (rowB < N) {
        const short* s = Xb + (size_t)rowB * 128 + cg2 * 16;
        b0 = *(const bf16x8*)s; b1 = *(const bf16x8*)(s + 8);
      }
    }
#pragma unroll
    for (int ks = 0; ks < 2; ks++) {
      int kk = ks * 32 + lg * 8;
      bf16x8 f[8], af[2];
#pragma unroll
      for (int s = 0; s < 8; s++)
        f[s] = *(const bf16x8*)(cur + (s * 16 + lr) * 72 + (kk ^ (s << 3)));
#pragma unroll
      for (int a = 0; a < 2; a++) {
        int ti = wid * 2 + a;
        af[a] = *(const bf16x8*)(cur + (ti * 16 + lr) * 72 + (kk ^ (ti << 3)));
      }
#pragma unroll
      for (int a = 0; a < 2; a++)
#pragma unroll
        for (int b = 0; b < 8; b++)
          acc[a][b] = __builtin_amdgcn_mfma_f32_16x16x32_bf16(af[a], f[b], acc[a][b], 0, 0, 0);
    }
    if (hn) {
#pragma unroll
      for (int j = 0; j < 8; j++) {
        cs[j]     += __uint_as_float(((unsigned)(unsigned short)a0[j]) << 16)
                   + __uint_as_float(((unsigned)(unsigned short)b0[j]) << 16);
        cs[j + 8] += __uint_as_float(((unsigned)(unsigned short)a1[j]) << 16)
                   + __uint_as_float(((unsigned)(unsigned short)b1[j]) << 16);
      }
#pragma unroll
      for (int j = 0; j < 8; j++) {
        nxt[(cg2 * 16 + j) * 72 + rsA]     = a0[j];
        nxt[(cg2 * 16 + 8 + j) * 72 + rsA] = a1[j];
        nxt[(cg2 * 16 + j) * 72 + rsB]     = b0[j];
        nxt[(cg2 * 16 + 8 + j) * 72 + rsB] = b1[j];
      }
    }
  }
#pragma unroll
  for (int a = 0; a < 2; a++)
#pragma unroll
    for (int b = 0; b < 8; b++)
#pragma unroll
      for (int r_ = 0; r_ < 4; r_++) {
        int ci = (wid * 2 + a) * 16 + lg * 4 + r_;
        int cj = b * 16 + lr;
        atomicAdd(&gram[ci * 128 + cj], acc[a][b][r_]);
      }
  if (tid < 128) lcs[tid] = 0.f;
  __syncthreads();
#pragma unroll
  for (int j = 0; j < 16; j++) atomicAdd(&lcs[cg2 * 16 + j], cs[j]);
  __syncthreads();
  if (tid < 128) atomicAdd(&csum[tid], lcs[tid]);
}

// ---------------- BN affine from Gram ----------------
__global__ __launch_bounds__(128) void k_finalizeG(const float* __restrict__ gram,
                                                   const float* __restrict__ csum,
                                                   const float* __restrict__ W1,
                                                   const float* __restrict__ b1,
                                                   const float* __restrict__ gamma,
                                                   const float* __restrict__ beta,
                                                   int N, float* Ac, float* Bc) {
  __shared__ float w[128], red[128], red2[128];
  int c = blockIdx.x, j = threadIdx.x;
  w[j] = W1[c * 128 + j];
  __syncthreads();
  float t = 0.f;
  for (int k = 0; k < 128; k++) t += gram[k * 128 + j] * w[k];
  red[j]  = t * w[j];
  red2[j] = w[j] * csum[j];
  __syncthreads();
  for (int off = 64; off > 0; off >>= 1) {
    if (j < off) { red[j] += red[j + off]; red2[j] += red2[j + off]; }
    __syncthreads();
  }
  if (j == 0) {
    float fn = (float)N;
    float q  = red[0] / fn;
    float md = red2[0] / fn;
    float b  = b1[c];
    float mu = md + b;
    float e2 = q + 2.f * b * md + b * b;
    float var = e2 - mu * mu;
    float s = gamma[c] * rsqrtf(var + BN_EPS);
    Ac[c] = s;
    Bc[c] = (b - mu) * s + beta[c];
  }
}

// ---------------- fallback stats (ws too small) ----------------
__global__ __launch_bounds__(256) void k_statsA(const float* __restrict__ X,
                                                const short* __restrict__ W1b,
                                                const float* __restrict__ b1, int N,
                                                float* chsum, float* chsq) {
  int tid = threadIdx.x;
  int wid = tid >> 6, lane = tid & 63;
  int lr = lane & 15, lg = lane >> 4;
  int p0 = blockIdx.x * 64;
  int wcol = wid * 64;
  f32x4 acc[4][4] = {};
  for (int kk = 0; kk < 4; kk++) {
    int k = kk * 32 + lg * 8;
    bf16x8 af[4], bfr[4];
    for (int m = 0; m < 4; m++) {
      int row = p0 + m * 16 + lr; if (row >= N) row = N - 1;
      af[m] = load_frag(X + (size_t)row * 128 + k);
    }
    for (int n = 0; n < 4; n++)
      bfr[n] = *(const bf16x8*)(W1b + (size_t)(wcol + n * 16 + lr) * 128 + k);
    for (int m = 0; m < 4; m++)
      for (int n = 0; n < 4; n++)
        acc[m][n] = __builtin_amdgcn_mfma_f32_16x16x32_bf16(af[m], bfr[n], acc[m][n], 0, 0, 0);
  }
  for (int n = 0; n < 4; n++) {
    int c = wcol + n * 16 + lr;
    float bv = b1[c];
    float s1 = 0.f, s2 = 0.f;
    for (int m = 0; m < 4; m++)
      for (int r = 0; r < 4; r++) {
        int row = p0 + m * 16 + lg * 4 + r;
        if (row < N) {
          float h = acc[m][n][r] + bv;
          s1 += h; s2 += h * h;
        }
      }
    s1 += __shfl_xor(s1, 16); s2 += __shfl_xor(s2, 16);
    s1 += __shfl_xor(s1, 32); s2 += __shfl_xor(s2, 32);
    if (lg == 0) { atomicAdd(&chsum[c], s1); atomicAdd(&chsq[c], s2); }
  }
}

__global__ void k_finalize(const float* chsum, const float* chsq, const float* b1,
                           const float* gamma, const float* beta, int N,
                           float* Ac, float* Bc) {
  int c = threadIdx.x;
  float fn = (float)N;
  float mu = chsum[c] / fn;
  float var = chsq[c] / fn - mu * mu;
  float s = gamma[c] * rsqrtf(var + BN_EPS);
  Ac[c] = s;
  Bc[c] = (b1[c] - mu) * s + beta[c];
}

// ---- fused GEMM1+BN+ReLU+GEMM2; 512 threads / 8 waves (64x32 per wave) ------------
template <bool XBF>
__global__ __launch_bounds__(512) void k_gemmB(const float* __restrict__ X,
                                               const short* __restrict__ Xb,
                                               const short* __restrict__ W1b,
                                               const short* __restrict__ W2b,
                                               const float* __restrict__ b2,
                                               const float* __restrict__ Ac,
                                               const float* __restrict__ Bc,
                                               const int* __restrict__ permvox,
                                               const int* __restrict__ lin,
                                               const int* __restrict__ rank,
                                               int N, unsigned* __restrict__ featU,
                                               int* __restrict__ bflag) {
  __shared__ char smem[64 * 264 * 2];   // axt(16K) -> ylds(32768) -> lmax(33792), time-sliced
  __shared__ int vox_s[64];
  __shared__ int perm_s[64];
  char* axt  = smem;                    // [64][128] bf16 row-major, byte ^ ((row&7)<<4)
  char* ylds = smem;
  unsigned short* lmax = (unsigned short*)smem;   // row-major [64][264] monotonic-u16

  int tid = threadIdx.x;
  int wid = tid >> 6, lane = tid & 63;
  int lr = lane & 15, lg = lane >> 4;
  int p0 = blockIdx.x * 64;
  int wcol = wid * 32;                  // 8 waves x 32 cols

  if (tid < 64) {
    int s = p0 + tid;
    if (XBF) {
      vox_s[tid] = (s < N) ? permvox[s] : -1;
    } else {
      int pp = permvox[(s < N) ? s : (N - 1)];
      perm_s[tid] = pp;
      vox_s[tid] = (s < N) ? rank[lin[pp]] : -1;
    }
  }
  __syncthreads();

  // stage A-tile: thread t -> row t>>3, 32B chunk t&7 (coalesced 256B per row)
  {
    int row = tid >> 3, chunk = tid & 7;
    int base = row * 256 + chunk * 32;
    int sw = (row & 7) << 4;
    bf16x8 a0, a1;
    if (XBF) {
      int grow = p0 + row; if (grow >= N) grow = N - 1;
      const short* src = Xb + (size_t)grow * 128 + chunk * 16;
      a0 = *(const bf16x8*)(src);
      a1 = *(const bf16x8*)(src + 8);
    } else {
      int prow = perm_s[row];
      const float* src = X + (size_t)prow * 128 + chunk * 16;
      a0 = load_frag(src);
      a1 = load_frag(src + 8);
    }
    *(bf16x8*)(axt + ((base)      ^ sw)) = a0;
    *(bf16x8*)(axt + ((base + 16) ^ sw)) = a1;
  }
  __syncthreads();

  // GEMM1: each wave computes h[64 x 32] slice = A(LDS) @ W1^T[:, wcol..wcol+31]
  f32x4 acc[4][2] = {};
  for (int kk = 0; kk < 4; kk++) {
    int kbyte = kk * 64 + lg * 16;
    bf16x8 af[4], bfr[2];
    int sw = (lr & 7) << 4;
    for (int m = 0; m < 4; m++) {
      int rowA = m * 16 + lr;
      af[m] = *(const bf16x8*)(axt + ((rowA * 256 + kbyte) ^ sw));
    }
    int k = kk * 32 + lg * 8;
    for (int n = 0; n < 2; n++)
      bfr[n] = *(const bf16x8*)(W1b + (size_t)(wcol + n * 16 + lr) * 128 + k);
    for (int m = 0; m < 4; m++)
      for (int n = 0; n < 2; n++)
        acc[m][n] = __builtin_amdgcn_mfma_f32_16x16x32_bf16(af[m], bfr[n], acc[m][n], 0, 0, 0);
  }
  __syncthreads();   // axt reads done before ylds overwrites

  // BN + ReLU -> swizzled bf16 in LDS (each wave writes its 32 columns)
  for (int n = 0; n < 2; n++) {
    int c = wcol + n * 16 + lr;
    float Av = Ac[c], Bv = Bc[c];
    int colb = c * 2;
    for (int m = 0; m < 4; m++)
      for (int r = 0; r < 4; r++) {
        int row = m * 16 + lg * 4 + r;
        float y = fmaxf(acc[m][n][r] * Av + Bv, 0.0f);
        int addr = (row * 512 + colb) ^ ((row & 7) << 4);
        *(short*)(ylds + addr) = f2bf(y);
      }
  }
  __syncthreads();

  // GEMM2: feats[64 x 32 slice] = y[64x256] @ W2^T[:, wcol..wcol+31]
  f32x4 acc2[4][2] = {};
  for (int kk = 0; kk < 8; kk++) {
    int k = kk * 32 + lg * 8;
    int kb = k * 2;
    bf16x8 af[4], bfr[2];
    for (int m = 0; m < 4; m++) {
      int row = m * 16 + lr;
      af[m] = *(const bf16x8*)(ylds + ((row * 512 + kb) ^ ((row & 7) << 4)));
    }
    for (int n = 0; n < 2; n++)
      bfr[n] = *(const bf16x8*)(W2b + (size_t)(wcol + n * 16 + lr) * 256 + k);
    for (int m = 0; m < 4; m++)
      for (int n = 0; n < 2; n++)
        acc2[m][n] = __builtin_amdgcn_mfma_f32_16x16x32_bf16(af[m], bfr[n], acc2[m][n], 0, 0, 0);
  }
  __syncthreads();   // all ylds reads complete before overwrite

  // single-shot staging: monotonic-u16 (encoded bf16); acc2 dies here
  for (int n = 0; n < 2; n++) {
    int c = wcol + n * 16 + lr;
    float bv = b2[c];
    for (int m = 0; m < 4; m++)
      for (int r = 0; r < 4; r++) {
        int row = m * 16 + lg * 4 + r;
        unsigned us = (unsigned)(unsigned short)f2bf(acc2[m][n][r] + bv);
        us = (us & 0x8000u) ? (~us & 0xFFFFu) : (us | 0x8000u);
        lmax[row * 264 + c] = (unsigned short)us;
      }
  }
  __syncthreads();

  // column pass on waves 0-3 (c = tid); waves 4-7 exit
  if (tid < 256) {
    int nrows = N - p0; if (nrows > 64) nrows = 64;
    int c = tid;
    unsigned run = 0;
    int vprev = vox_s[0];
    int run_start = 0;
    for (int row = 0; row < nrows; row++) {
      int v = vox_s[row];
      if (v != vprev) {
        size_t idx = (size_t)vprev * 256 + c;
        if (run_start > 0) {
          ((float*)featU)[idx] = dec16(run);            // block-interior: store decoded
        } else {
          atomicMax(&featU[idx], run << 16);            // may extend previous block
          if (tid == 0) bflag[vprev] = FLAG_MAGIC;
        }
        run = 0; vprev = v; run_start = row;
      }
      run = max(run, (unsigned)lmax[row * 264 + c]);
    }
    if (vprev >= 0) {
      atomicMax(&featU[(size_t)vprev * 256 + c], run << 16);  // may extend next block
      if (tid == 0) bflag[vprev] = FLAG_MAGIC;
    }
  }
}

// ------- decode boundary voxels via list (xbf path): claim with atomicExch ---------
__global__ void k_decodeL(const int* __restrict__ permvox, int N,
                          int* __restrict__ bflag, unsigned* __restrict__ featU) {
  __shared__ int claim;
  int inst = blockIdx.x;         // 2 per 64-row tile (first/last row's voxel)
  int k = inst >> 1;
  int s = k * 64 + ((inst & 1) ? 63 : 0);
  if (s >= N) s = N - 1;
  int v = permvox[s];
  if (threadIdx.x == 0)
    claim = (atomicExch(&bflag[v], 0) == FLAG_MAGIC) ? 1 : 0;
  __syncthreads();
  if (!claim) return;
  size_t idx = (size_t)v * 256 + threadIdx.x;
  featU[idx] = __float_as_uint(dec16(featU[idx] >> 16));
}

// ---------------- decode all (fallback path) ----------------
__global__ void k_decode(unsigned* featU, const int* __restrict__ bflag, size_t n) {
  size_t i = (size_t)blockIdx.x * blockDim.x + threadIdx.x;
  size_t stride = (size_t)gridDim.x * blockDim.x;
  for (; i < n; i += stride) {
    if (bflag[i >> 8] == FLAG_MAGIC) {
      unsigned e = featU[i] >> 16;
      ((float*)featU)[i] = dec16(e);
    }
  }
}

extern "C" void kernel_launch(void* const* d_in, const int* in_sizes, int n_in,
                              void* d_out, int out_size, void* d_ws, size_t ws_size,
                              hipStream_t stream) {
  const float* xyz   = (const float*)d_in[0];
  const float* X     = (const float*)d_in[1];
  const int*   offs  = (const int*)d_in[2];
  const float* W1    = (const float*)d_in[3];
  const float* b1    = (const float*)d_in[4];
  const float* gamma = (const float*)d_in[5];
  const float* beta  = (const float*)d_in[6];
  const float* W2    = (const float*)d_in[7];
  const float* b2    = (const float*)d_in[8];

  int N  = in_sizes[0] / 3;
  int nb = in_sizes[2];
  int M  = (out_size - nb - N) / 259;
  if (M <= 0) return;

  char* ws = (char*)d_ws;
  unsigned* gstart = (unsigned*)(ws + WS_START);
  int*   gdims  = (int*)(ws + WS_DIMS);
  float* chsum  = (float*)(ws + WS_CHSUM);
  float* chsq   = (float*)(ws + WS_CHSQ);
  float* Ac     = (float*)(ws + WS_AC);
  float* Bc     = (float*)(ws + WS_BC);
  short* W1b    = (short*)(ws + WS_W1B);
  short* W2b    = (short*)(ws + WS_W2B);
  float* gram   = (float*)(ws + WS_GRAM);
  float* csum   = (float*)(ws + WS_CSUM);
  int*   hist   = (int*)(ws + WS_HIST);
  int*   rank   = (int*)(ws + WS_RANK);
  int*   cursor = (int*)(ws + WS_CURS);   // after k_scatter, reused as boundary flag
  int2*  bsum   = (int2*)(ws + WS_BSUM);
  float* xyzs   = (float*)(ws + WS_XYZS);
  int*   lin    = (int*)(ws + WS_LIN);
  int*   permvox = (int*)(ws + WS_PERM);  // xbf: vox per sorted slot; else perm
  short* Xb     = (short*)(ws + WS_XB);

  size_t req = (size_t)WS_XB + (size_t)N * 128 * 2;
  bool xbf = ws_size >= req;

  float* out_xyz  = (float*)d_out;
  float* out_feat = out_xyz + (size_t)3 * M;
  float* out_off  = out_feat + (size_t)M * 256;
  float* out_inv  = out_off + nb;
  unsigned* featU = (unsigned*)out_feat;

  int npb = (N + 255) / 256;
  int ngb = (N + 63) / 64;
  int ngr = (N + GCHUNK - 1) / GCHUNK;

  hipLaunchKernelGGL(k_init, dim3(2048), dim3(256), 0, stream,
                     featU, xbf ? (size_t)0 : (size_t)M * 256, hist, xyzs,
                     chsum, chsq, gram, csum, gstart, W1, W2, W1b, W2b);
  hipLaunchKernelGGL(k_min, dim3(npb), dim3(256), 0, stream, xyz, offs, N, nb, gstart);
  hipLaunchKernelGGL(k_hist, dim3(npb), dim3(256), 0, stream,
                     xyz, offs, N, nb, gstart, lin, hist, xyzs, gdims);
  hipLaunchKernelGGL(k_scanA, dim3(64), dim3(1024), 0, stream, hist, gdims, nb, bsum);
  hipLaunchKernelGGL(k_scanB, dim3(64), dim3(1024), 0, stream,
                     hist, gdims, nb, bsum, rank, cursor, xyzs, out_xyz, out_off);
  if (xbf) {
    hipLaunchKernelGGL((k_scatter<true>), dim3(npb), dim3(256), 0, stream,
                       lin, rank, cursor, N, X, Xb, permvox, out_inv);
    hipLaunchKernelGGL(k_initb, dim3(2 * ngb), dim3(256), 0, stream,
                       permvox, N, featU);
    hipLaunchKernelGGL(k_gram, dim3(ngr), dim3(256), 0, stream, Xb, N, gram, csum);
    hipLaunchKernelGGL(k_finalizeG, dim3(256), dim3(128), 0, stream,
                       gram, csum, W1, b1, gamma, beta, N, Ac, Bc);
    hipLaunchKernelGGL((k_gemmB<true>), dim3(ngb), dim3(512), 0, stream,
                       X, Xb, W1b, W2b, b2, Ac, Bc, permvox, lin, rank, N, featU, cursor);
    hipLaunchKernelGGL(k_decodeL, dim3(2 * ngb), dim3(256), 0, stream,
                       permvox, N, cursor, featU);
  } else {
    hipLaunchKernelGGL((k_scatter<false>), dim3(npb), dim3(256), 0, stream,
                       lin, rank, cursor, N, X, Xb, permvox, out_inv);
    hipLaunchKernelGGL(k_statsA, dim3(ngb), dim3(256), 0, stream,
                       X, W1b, b1, N, chsum, chsq);
    hipLaunchKernelGGL(k_finalize, dim3(1), dim3(256), 0, stream,
                       chsum, chsq, b1, gamma, beta, N, Ac, Bc);
    hipLaunchKernelGGL((k_gemmB<false>), dim3(ngb), dim3(512), 0, stream,
                       X, Xb, W1b, W2b, b2, Ac, Bc, permvox, lin, rank, N, featU, cursor);
    hipLaunchKernelGGL(k_decode, dim3(2048), dim3(256), 0, stream,
                       featU, cursor, (size_t)M * 256);
  }
}